// Round 8
// baseline (549.970 us; speedup 1.0000x reference)
//
#include <hip/hip_runtime.h>

// ---------------- problem constants ----------------
#define B_     4
#define T_     512
#define DIN    4096
#define H_     32
#define G_     8
#define HD_    128
#define S_     4096
#define CACHE_ 3584
#define M_     2048          // B*T
#define NQKV   6144          // H*HD + 2*G*HD
#define SCALE  0.08838834764831843f  // 1/sqrt(128)
#define LOG2E  1.4426950408889634f
#define QSC    (SCALE * LOG2E)       // folded into Q at rope time -> softmax in exp2 domain

typedef __attribute__((ext_vector_type(4)))  float  f32x4;
typedef __attribute__((ext_vector_type(16))) float  f32x16;
typedef __attribute__((ext_vector_type(8)))  short  s16x8;   // 8 bf16 (4 VGPRs) MFMA frag
typedef __attribute__((ext_vector_type(4)))  unsigned short u16x4;
typedef __attribute__((ext_vector_type(8)))  unsigned short u16x8;
typedef __attribute__((ext_vector_type(4)))  unsigned int   u32x4;
typedef unsigned short u16;
typedef unsigned int   u32;

__device__ __forceinline__ u16 f2bf(float f) {
  u32 u = __builtin_bit_cast(u32, f);
  return (u16)((u + 0x7fffu + ((u >> 16) & 1u)) >> 16);   // RNE
}
__device__ __forceinline__ float bf2f(u16 h) {
  return __builtin_bit_cast(float, (u32)h << 16);
}
__device__ __forceinline__ f32x4 mfma16(s16x8 a, s16x8 b, f32x4 c) {
  return __builtin_amdgcn_mfma_f32_16x16x32_bf16(a, b, c, 0, 0, 0);
}
__device__ __forceinline__ u32 pkbf(float a, float b) {   // pack 2 f32 -> 2 bf16 (RNE)
  u32 r; asm("v_cvt_pk_bf16_f32 %0, %1, %2" : "=v"(r) : "v"(a), "v"(b)); return r;
}
// async global->LDS, 16B per lane; LDS dest is wave-uniform base + lane*16
__device__ __forceinline__ void gload_lds16(const void* g, void* l) {
  __builtin_amdgcn_global_load_lds((__attribute__((address_space(1))) void*)g,
                                   (__attribute__((address_space(3))) void*)l, 16, 0, 0);
}

// ---------------- phase 0: x f32 -> bf16 ----------------
__global__ __launch_bounds__(256) void k_cvt_x(const float* __restrict__ x, u16* __restrict__ xb) {
  size_t i = ((size_t)blockIdx.x * 256 + threadIdx.x) * 4;
  f32x4 v = *(const f32x4*)(x + i);
  u16x4 o = { f2bf(v[0]), f2bf(v[1]), f2bf(v[2]), f2bf(v[3]) };
  *(u16x4*)(xb + i) = o;
}

// ---------------- phase 0: weight transpose f32[K][ldn] -> bf16[ldn][4096] ----------------
__global__ __launch_bounds__(256) void k_twt(const float* __restrict__ src, int ldn,
                                             u16* __restrict__ dst) {
  __shared__ float tile[64][68];
  int k0 = blockIdx.x * 64, n0 = blockIdx.y * 64;
  int t = threadIdx.x;
  int rr = t >> 4, cc = (t & 15) * 4;
#pragma unroll
  for (int p = 0; p < 4; ++p) {
    int r = p * 16 + rr;
    f32x4 v = *(const f32x4*)(src + (size_t)(k0 + r) * ldn + n0 + cc);
    tile[r][cc] = v[0]; tile[r][cc + 1] = v[1]; tile[r][cc + 2] = v[2]; tile[r][cc + 3] = v[3];
  }
  __syncthreads();
#pragma unroll
  for (int p = 0; p < 4; ++p) {
    int n = p * 16 + rr;
    u16x4 o = { f2bf(tile[cc][n]), f2bf(tile[cc + 1][n]), f2bf(tile[cc + 2][n]), f2bf(tile[cc + 3][n]) };
    *(u16x4*)(dst + (size_t)(n0 + n) * 4096 + k0 + cc) = o;
  }
}

// ---------------- phase 0: prev_k -> k_all f32 copy + bf16 ----------------
__global__ __launch_bounds__(256) void k_prep_k(const float* __restrict__ pk,
                                                float* __restrict__ k_all, u16* __restrict__ kb) {
  int bg = blockIdx.y;
  size_t si = ((size_t)blockIdx.x * 256 + threadIdx.x) * 4;   // < 3584*128
  f32x4 v = *(const f32x4*)(pk + (size_t)bg * CACHE_ * HD_ + si);
  size_t dof = (size_t)bg * S_ * HD_ + si;
  *(f32x4*)(k_all + dof) = v;
  u16x4 o = { f2bf(v[0]), f2bf(v[1]), f2bf(v[2]), f2bf(v[3]) };
  *(u16x4*)(kb + dof) = o;
}

// ---------------- phase 0: prev_v -> v_all f32 copy + transposed bf16 v_t[bg][hd][s] ----------------
__global__ __launch_bounds__(256) void k_prep_v(const float* __restrict__ pv,
                                                float* __restrict__ v_all, u16* __restrict__ vt) {
  __shared__ float tile[64][132];
  int bg = blockIdx.y, s0 = blockIdx.x * 64;
  int t = threadIdx.x;
  const float* src = pv + ((size_t)bg * CACHE_ + s0) * HD_;
  float* dc = v_all + ((size_t)bg * S_ + s0) * HD_;
  int r8 = t >> 5, c4 = (t & 31) * 4;
#pragma unroll
  for (int p = 0; p < 8; ++p) {
    int r = p * 8 + r8;
    f32x4 v = *(const f32x4*)(src + (size_t)r * HD_ + c4);
    *(f32x4*)(dc + (size_t)r * HD_ + c4) = v;
    tile[r][c4] = v[0]; tile[r][c4 + 1] = v[1]; tile[r][c4 + 2] = v[2]; tile[r][c4 + 3] = v[3];
  }
  __syncthreads();
  int hr = t >> 4, s4 = (t & 15) * 4;
#pragma unroll
  for (int p = 0; p < 8; ++p) {
    int hd = p * 16 + hr;
    u16x4 o = { f2bf(tile[s4][hd]), f2bf(tile[s4 + 1][hd]), f2bf(tile[s4 + 2][hd]), f2bf(tile[s4 + 3][hd]) };
    *(u16x4*)(vt + ((size_t)bg * HD_ + hd) * S_ + s0 + s4) = o;
  }
}

// ---------------- GEMM v2: C[M][N] = A[M][K]bf16 @ Bt[N][K]bf16 ----------------
template<int BM, bool OUT_F32>
__global__ __launch_bounds__(512, 1) void k_gemm2(const u16* __restrict__ A, const u16* __restrict__ Bt,
                                                  void* __restrict__ Cp, int M, int N, int K) {
  constexpr int MI = BM / 32;        // A-frag repeats per wave (8 or 4)
  constexpr int LA = BM / 64;        // A stage loads/thread per K-tile (4 or 2)
  __shared__ u16 As[2 * BM * 64];    // [buf][BM][64], chunk16 ch' = ch ^ (row&7)
  __shared__ u16 Bs[2 * 256 * 64];
  const int tid = threadIdx.x, w = tid >> 6, lane = tid & 63;
  const int wr = w >> 2, wc = w & 3;             // wave tile: rows wr*(BM/2), cols wc*64
  const int cl = lane & 15, khi = lane >> 4;
  // --- T1: bijective XCD swizzle, column-major (bm fast) ---
  const int Mt = M / BM;
  const int nwg = gridDim.x;
  const int q = nwg >> 3, r8 = nwg & 7;
  const int xcd = blockIdx.x & 7, pos = blockIdx.x >> 3;
  const int wgid = (xcd < r8 ? xcd * (q + 1) : r8 * (q + 1) + (xcd - r8) * q) + pos;
  const int m0 = (wgid % Mt) * BM, n0 = (wgid / Mt) * 256;
  // --- staging addresses (inverse-swizzled global source) ---
  const int rb = tid >> 3;                       // 0..63
  const int csw = ((tid & 7) ^ (rb & 7)) * 8;    // element offset, pre-swizzled
  const u16* aS = A  + (size_t)(m0 + rb) * K + csw;
  const u16* bS = Bt + (size_t)(n0 + rb) * K + csw;
  u16* aD = As + w * 512;                        // + buf*BM*64 + i*4096; lane*16B implicit
  u16* bD = Bs + w * 512;
  // --- swizzled read chunk offsets (row&7 == cl&7 for all frags) ---
  const int ck0 = ((0 + khi) ^ (cl & 7)) * 8;
  const int ck1 = ((4 + khi) ^ (cl & 7)) * 8;
  const int NT = K >> 6;
  f32x4 acc[MI][4] = {};

#define STAGE_(buf, tt)                                                                   \
  do {                                                                                    \
    _Pragma("unroll")                                                                     \
    for (int i = 0; i < LA; ++i)                                                          \
      gload_lds16(aS + (size_t)(i * 64) * K + (size_t)(tt) * 64, aD + (buf) * (BM * 64) + i * 4096); \
    _Pragma("unroll")                                                                     \
    for (int i = 0; i < 4; ++i)                                                           \
      gload_lds16(bS + (size_t)(i * 64) * K + (size_t)(tt) * 64, bD + (buf) * (256 * 64) + i * 4096); \
  } while (0)
#define VMCNT_L_()                                                                        \
  do {                                                                                    \
    if constexpr (BM == 256) asm volatile("s_waitcnt vmcnt(8)" ::: "memory");             \
    else                     asm volatile("s_waitcnt vmcnt(6)" ::: "memory");             \
  } while (0)

  STAGE_(0, 0);
  STAGE_(1, 1);
  VMCNT_L_();
  __builtin_amdgcn_sched_barrier(0);
  __builtin_amdgcn_s_barrier();
  __builtin_amdgcn_sched_barrier(0);

  for (int t = 0; t < NT; ++t) {
    const int buf = t & 1;
    const int ab = buf * (BM * 64) + (wr * (BM / 2) + cl) * 64;
    const int bb = buf * (256 * 64) + (wc * 64 + cl) * 64;
#pragma unroll
    for (int kk = 0; kk < 2; ++kk) {
      const int ck = kk ? ck1 : ck0;
      s16x8 bf4[4], af[MI];
#pragma unroll
      for (int ni = 0; ni < 4; ++ni) bf4[ni] = *(const s16x8*)(Bs + bb + ni * 16 * 64 + ck);
#pragma unroll
      for (int mi = 0; mi < MI; ++mi) af[mi] = *(const s16x8*)(As + ab + mi * 16 * 64 + ck);
      __builtin_amdgcn_s_setprio(1);
#pragma unroll
      for (int mi = 0; mi < MI; ++mi)
#pragma unroll
        for (int ni = 0; ni < 4; ++ni)
          acc[mi][ni] = mfma16(af[mi], bf4[ni], acc[mi][ni]);
      __builtin_amdgcn_s_setprio(0);
    }
    __builtin_amdgcn_sched_barrier(0);
    __builtin_amdgcn_s_barrier();     // all waves done reading buf (ds data already retired pre-MFMA)
    __builtin_amdgcn_sched_barrier(0);
    if (t + 2 < NT) STAGE_(buf, t + 2);
    VMCNT_L_();                       // tile t+1 landed; t+2's loads stay in flight (T4)
    __builtin_amdgcn_sched_barrier(0);
    __builtin_amdgcn_s_barrier();
    __builtin_amdgcn_sched_barrier(0);
  }
#undef STAGE_
#undef VMCNT_L_
  const int rl = khi * 4;
#pragma unroll
  for (int mi = 0; mi < MI; ++mi)
#pragma unroll
    for (int ni = 0; ni < 4; ++ni) {
      int col = n0 + wc * 64 + ni * 16 + cl;
#pragma unroll
      for (int r = 0; r < 4; ++r) {
        int rw = m0 + wr * (BM / 2) + mi * 16 + rl + r;
        if (OUT_F32) ((float*)Cp)[(size_t)rw * N + col] = acc[mi][ni][r];
        else         ((u16*)Cp)[(size_t)rw * N + col]   = f2bf(acc[mi][ni][r]);
      }
    }
}

// ---------------- RoPE + scatter (Q pre-scaled by SCALE*log2e for exp2-domain softmax) ----------------
__global__ __launch_bounds__(256) void k_rope(const u16* __restrict__ qkv, const float* __restrict__ cosT,
                                              const float* __restrict__ sinT, const int* __restrict__ sp,
                                              u16* __restrict__ qr, u16* __restrict__ kb,
                                              float* __restrict__ k_all, float* __restrict__ v_all) {
  int bt = blockIdx.x;
  int b = bt >> 9, t = bt & 511;
  int pos = sp[b] + t;
  const u16* row = qkv + (size_t)bt * NQKV;
  for (int idx = threadIdx.x; idx < 2560; idx += 256) {   // 40 roped heads * 64 pairs
    int head = idx >> 6, d = idx & 63;
    float c = cosT[pos * HD_ + d], s = sinT[pos * HD_ + d];
    float x1 = bf2f(row[head * HD_ + d]);
    float x2 = bf2f(row[head * HD_ + d + 64]);
    float y1 = x1 * c - x2 * s;
    float y2 = x2 * c + x1 * s;
    if (head < 32) {
      size_t o = (((size_t)b * H_ + head) * T_ + t) * HD_ + d;
      qr[o] = f2bf(y1 * QSC); qr[o + 64] = f2bf(y2 * QSC);
    } else {
      int g = head - 32;
      size_t o = (((size_t)b * G_ + g) * S_ + CACHE_ + t) * HD_ + d;
      kb[o] = f2bf(y1); kb[o + 64] = f2bf(y2);
      k_all[o] = y1; k_all[o + 64] = y2;
    }
  }
  for (int idx = threadIdx.x; idx < 1024; idx += 256) {   // v passthrough (f32 copy only)
    int g = idx >> 7;
    float v = bf2f(row[5120 + idx]);
    size_t o = (((size_t)b * G_ + g) * S_ + CACHE_ + t) * HD_ + (idx & 127);
    v_all[o] = v;
  }
}

// ---------------- transpose new-V slice into v_t[bg][hd][CACHE_..S] ----------------
__global__ __launch_bounds__(256) void k_tv_new(const u16* __restrict__ qkv, u16* __restrict__ vt) {
  __shared__ u16 tile[64][72];
  int bg = blockIdx.y;
  int b = bg >> 3, g = bg & 7;
  int tt = blockIdx.x >> 1, ht = blockIdx.x & 1;
  int t0 = tt * 64, hd0 = ht * 64;
  int t = threadIdx.x;
  int rr = t >> 3, c8 = (t & 7) * 8;
#pragma unroll
  for (int p = 0; p < 2; ++p) {
    int r = p * 32 + rr;
    *(u16x8*)(&tile[r][c8]) =
      *(const u16x8*)(qkv + (size_t)(b * T_ + t0 + r) * NQKV + 5120 + g * HD_ + hd0 + c8);
  }
  __syncthreads();
  int hr = t >> 4, s4 = (t & 15) * 4;
#pragma unroll
  for (int p = 0; p < 4; ++p) {
    int hd = p * 16 + hr;
    u16x4 o = { tile[s4][hd], tile[s4 + 1][hd], tile[s4 + 2][hd], tile[s4 + 3][hd] };
    *(u16x4*)(vt + ((size_t)bg * HD_ + hd0 + hd) * S_ + CACHE_ + t0 + s4) = o;
  }
}

// ---------------- flash attention v6: 8 waves x 32 q, T15 two-tile pipeline ----------------
// Pairs of KV tiles per iteration from 4 LDS buffer pairs (128 KiB): QK(j0)+QK(j1) issued
// back-to-back, softmax(j0)/PV(j0) overlaps QK(j1) MFMAs; softmax(j1) overlaps PV(j0).
// One barrier per pair. Row-sum via 8 parallel partial accumulators (breaks 64-deep add chain).
__global__ __launch_bounds__(512) void k_attn(const u16* __restrict__ Q, const u16* __restrict__ Kc,
                                              const u16* __restrict__ Vt, const int* __restrict__ sp,
                                              u16* __restrict__ ctx) {
  __shared__ u16 Ks[4][64 * 128];   // 4 K-tile buffers, chunk c at c ^ (row&15)
  __shared__ u16 Vs[4][128 * 64];   // 4 V-tile buffers, chunk c at c ^ (row&7)
  // XCD grouping: 8 consecutive wgids share one (b,g) KV slab; each XCD owns 4 slabs.
  const int xcd = blockIdx.x & 7, pos = blockIdx.x >> 3;
  const int wgid = xcd * 32 + pos;                 // nwg = 256
  const int qh = wgid & 1, hq = (wgid >> 1) & 3, bg = wgid >> 3;
  const int b = bg >> 3, g = bg & 7, h = g * 4 + hq;
  const int tid = threadIdx.x, w = tid >> 6, lane = tid & 63;
  const int l31 = lane & 31, hh = lane >> 5;
  const int cache = sp[b];
  const int qbase = qh * 256;
  const int qtok = qbase + w * 32 + l31;           // this lane's softmax q-row
  const size_t kvoff = (size_t)bg * S_ * HD_;
  const u16* kp = Kc + kvoff;
  const u16* vp = Vt + kvoff;
  s16x8 qreg[8];
  {
    const u16* qb = Q + ((size_t)(b * H_ + h) * T_ + qtok) * HD_;
#pragma unroll
    for (int s = 0; s < 8; ++s) qreg[s] = *(const s16x8*)(qb + s * 16 + hh * 8);
  }
  f32x16 acc[4] = {};
  float mr = -1e30f, ls = 0.f;
  const int krow = w * 8 + (lane >> 3), kch = lane & 7;
  const int vrow = w * 16 + (lane >> 2), vch = lane & 3;
  const int kswz = (krow & 15) << 3;               // element offsets
  const int vswz = (vrow & 7) << 3;
  const int rdswzK = (l31 & 15) << 3;
  const int rdswzV = (l31 & 7) << 3;
  const int jm = (cache + qbase + w * 32) >> 6;    // first tile needing mask (per wave)
  const int NT = ((cache + qbase + 255) >> 6) + 1; // block-uniform tile count
  const int kvlim = cache + qtok;

  auto ldK = [&](int t, u16x8& a, u16x8& c) {
    a = *(const u16x8*)(kp + (size_t)(t * 64 + krow) * HD_ + kch * 8);
    c = *(const u16x8*)(kp + (size_t)(t * 64 + krow) * HD_ + (kch + 8) * 8);
  };
  auto ldV = [&](int t, u16x8& a, u16x8& c) {
    a = *(const u16x8*)(vp + (size_t)vrow * S_ + t * 64 + vch * 8);
    c = *(const u16x8*)(vp + (size_t)vrow * S_ + t * 64 + (vch + 4) * 8);
  };
  auto stK = [&](int slot, u16x8 a, u16x8 c) {
    *(u16x8*)(Ks[slot] + krow * 128 + ((kch * 8) ^ kswz))       = a;
    *(u16x8*)(Ks[slot] + krow * 128 + (((kch + 8) * 8) ^ kswz)) = c;
  };
  auto stV = [&](int slot, u16x8 a, u16x8 c) {
    *(u16x8*)(Vs[slot] + vrow * 64 + ((vch * 8) ^ vswz))        = a;
    *(u16x8*)(Vs[slot] + vrow * 64 + (((vch + 4) * 8) ^ vswz))  = c;
  };
  auto qk = [&](const u16* KsB, f32x16* sa) {
    f32x16 a = {}, c = {};
    __builtin_amdgcn_s_setprio(1);
#pragma unroll
    for (int s = 0; s < 8; ++s) {
      s16x8 ka = *(const s16x8*)(KsB + l31 * 128 + ((s * 16 + hh * 8) ^ rdswzK));
      a = __builtin_amdgcn_mfma_f32_32x32x16_bf16(ka, qreg[s], a, 0, 0, 0);
    }
#pragma unroll
    for (int s = 0; s < 8; ++s) {
      s16x8 ka = *(const s16x8*)(KsB + (32 + l31) * 128 + ((s * 16 + hh * 8) ^ rdswzK));
      c = __builtin_amdgcn_mfma_f32_32x32x16_bf16(ka, qreg[s], c, 0, 0, 0);
    }
    __builtin_amdgcn_s_setprio(0);
    sa[0] = a; sa[1] = c;
  };
  auto softpv = [&](f32x16* sa, const u16* VsB, int jt) {
    // causal mask (only tiles >= jm can have masked kv)
    if (jt >= jm) {
#pragma unroll
      for (int r = 0; r < 16; ++r) {
        int kv = jt * 64 + (r & 3) + 8 * (r >> 2) + 4 * hh;
        if (kv > kvlim)      sa[0][r] = -1e30f;
        if (kv + 32 > kvlim) sa[1][r] = -1e30f;
      }
    }
    // row max: max3 tree (T17) + one lane-half exchange
    float mx;
    {
      float t[16];
#pragma unroll
      for (int r = 0; r < 16; ++r) t[r] = fmaxf(sa[0][r], sa[1][r]);
#define F3_(a, b, c) fmaxf(fmaxf(a, b), c)
      float u0 = F3_(t[0], t[1], t[2]);
      float u1 = F3_(t[3], t[4], t[5]);
      float u2 = F3_(t[6], t[7], t[8]);
      float u3 = F3_(t[9], t[10], t[11]);
      float u4 = F3_(t[12], t[13], t[14]);
      float lm = fmaxf(F3_(u0, u1, u2), F3_(u3, u4, t[15]));
#undef F3_
      mx = fmaxf(lm, __shfl_xor(lm, 32));
    }
    // defer-max (T13)
    if (__any(mx > mr + 8.f)) {
      float nm = fmaxf(mr, mx);
      float al = __builtin_amdgcn_exp2f(mr - nm);
      mr = nm; ls *= al;
#pragma unroll
      for (int r = 0; r < 16; ++r) {
        float ar = __shfl(al, (r & 3) + 8 * (r >> 2) + 4 * hh, 64);
        acc[0][r] *= ar; acc[1][r] *= ar; acc[2][r] *= ar; acc[3][r] *= ar;
      }
    }
    // exp2 + row sum with 8 parallel partials (breaks the serial add chain)
    float p0 = 0.f, p1 = 0.f, p2 = 0.f, p3 = 0.f, p4 = 0.f, p5 = 0.f, p6 = 0.f, p7 = 0.f;
#pragma unroll
    for (int r = 0; r < 16; r += 4) {
      float e0 = __builtin_amdgcn_exp2f(sa[0][r]     - mr);
      float e1 = __builtin_amdgcn_exp2f(sa[0][r + 1] - mr);
      float e2 = __builtin_amdgcn_exp2f(sa[0][r + 2] - mr);
      float e3 = __builtin_amdgcn_exp2f(sa[0][r + 3] - mr);
      sa[0][r] = e0; sa[0][r + 1] = e1; sa[0][r + 2] = e2; sa[0][r + 3] = e3;
      p0 += e0; p1 += e1; p2 += e2; p3 += e3;
    }
#pragma unroll
    for (int r = 0; r < 16; r += 4) {
      float e0 = __builtin_amdgcn_exp2f(sa[1][r]     - mr);
      float e1 = __builtin_amdgcn_exp2f(sa[1][r + 1] - mr);
      float e2 = __builtin_amdgcn_exp2f(sa[1][r + 2] - mr);
      float e3 = __builtin_amdgcn_exp2f(sa[1][r + 3] - mr);
      sa[1][r] = e0; sa[1][r + 1] = e1; sa[1][r + 2] = e2; sa[1][r + 3] = e3;
      p4 += e0; p5 += e1; p6 += e2; p7 += e3;
    }
    float rs = ((p0 + p1) + (p2 + p3)) + ((p4 + p5) + (p6 + p7));
    rs += __shfl_xor(rs, 32);
    ls += rs;
    // pack P (D-layout) into 4 MFMA A-frags, in-register (T12 pattern)
    s16x8 pf[4];
#pragma unroll
    for (int sb = 0; sb < 2; ++sb) {
      u32 a0 = pkbf(sa[sb][0],  sa[sb][1]),  a1 = pkbf(sa[sb][2],  sa[sb][3]);
      u32 b0 = pkbf(sa[sb][4],  sa[sb][5]),  b1 = pkbf(sa[sb][6],  sa[sb][7]);
      u32 c0 = pkbf(sa[sb][8],  sa[sb][9]),  c1 = pkbf(sa[sb][10], sa[sb][11]);
      u32 d0 = pkbf(sa[sb][12], sa[sb][13]), d1 = pkbf(sa[sb][14], sa[sb][15]);
      u32 xa0 = __shfl_xor(a0, 32), xa1 = __shfl_xor(a1, 32);
      u32 xb0 = __shfl_xor(b0, 32), xb1 = __shfl_xor(b1, 32);
      u32 xc0 = __shfl_xor(c0, 32), xc1 = __shfl_xor(c1, 32);
      u32 xd0 = __shfl_xor(d0, 32), xd1 = __shfl_xor(d1, 32);
      u32x4 f0 = { hh ? xb0 : a0, hh ? xb1 : a1, hh ? b0 : xa0, hh ? b1 : xa1 };
      u32x4 f1 = { hh ? xd0 : c0, hh ? xd1 : c1, hh ? d0 : xc0, hh ? d1 : xc1 };
      pf[sb * 2]     = __builtin_bit_cast(s16x8, f0);
      pf[sb * 2 + 1] = __builtin_bit_cast(s16x8, f1);
    }
    // O += P V
    __builtin_amdgcn_s_setprio(1);
#pragma unroll
    for (int hb = 0; hb < 4; ++hb) {
      const int vro = hb * 32 + l31;
#pragma unroll
      for (int kb = 0; kb < 4; ++kb) {
        s16x8 vb = *(const s16x8*)(VsB + vro * 64 + ((kb * 16 + hh * 8) ^ rdswzV));
        acc[hb] = __builtin_amdgcn_mfma_f32_32x32x16_bf16(pf[kb], vb, acc[hb], 0, 0, 0);
      }
    }
    __builtin_amdgcn_s_setprio(0);
  };

  // prologue: tiles 0,1 -> LDS pair0; prefetch tiles 2,3 -> regs
  u16x8 ka0, ka1, va0, va1, kb0, kb1, vb0, vb1;
  ldK(0, ka0, ka1); ldV(0, va0, va1);
  stK(0, ka0, ka1); stV(0, va0, va1);
  ldK(1, kb0, kb1); ldV(1, vb0, vb1);
  stK(1, kb0, kb1); stV(1, vb0, vb1);
  {
    int c2 = (2 < NT) ? 2 : NT - 1, c3 = (3 < NT) ? 3 : NT - 1;
    ldK(c2, ka0, ka1); ldV(c2, va0, va1);
    ldK(c3, kb0, kb1); ldV(c3, vb0, vb1);
  }
  __syncthreads();

  const int NP = NT >> 1;
  f32x16 sa0[2], sa1[2];
  for (int p = 0; p < NP; ++p) {
    const int j0 = 2 * p, j1 = j0 + 1;
    const int cu = (p & 1) << 1, nx = cu ^ 2;
    // issue QK for both tiles back-to-back (second overlaps first's softmax)
    qk(Ks[cu], sa0);
    qk(Ks[cu + 1], sa1);
    // stage tiles j0+2, j1+2 into the idle pair
    if (j0 + 2 < NT) { stK(nx, ka0, ka1);     stV(nx, va0, va1); }
    if (j1 + 2 < NT) { stK(nx + 1, kb0, kb1); stV(nx + 1, vb0, vb1); }
    // prefetch tiles j0+4, j1+4 -> regs
    if (j0 + 4 < NT) { ldK(j0 + 4, ka0, ka1); ldV(j0 + 4, va0, va1); }
    if (j1 + 4 < NT) { ldK(j1 + 4, kb0, kb1); ldV(j1 + 4, vb0, vb1); }
    // softmax+PV tile j0 (QK(j1) MFMAs in flight underneath), then tile j1
    softpv(sa0, Vs[cu], j0);
    softpv(sa1, Vs[cu + 1], j1);
    __syncthreads();   // publishes staged pair, retires reads of current pair
  }
  if (NT & 1) {        // odd tail: last tile staged into slot ((NP&1)<<1)
    const int cu = (NP & 1) << 1;
    qk(Ks[cu], sa0);
    softpv(sa0, Vs[cu], NT - 1);
  }
  // epilogue: normalize rows (ls lives at lane l31==row) and store ctx
  float inv = 1.0f / ls;
#pragma unroll
  for (int r = 0; r < 16; ++r) {
    int ql = (r & 3) + 8 * (r >> 2) + 4 * hh;
    float ivr = __shfl(inv, ql, 64);
    u16* cb = ctx + ((size_t)(b * T_ + qbase + w * 32 + ql)) * 4096 + h * HD_ + l31;
    cb[0]  = f2bf(acc[0][r] * ivr);
    cb[32] = f2bf(acc[1][r] * ivr);
    cb[64] = f2bf(acc[2][r] * ivr);
    cb[96] = f2bf(acc[3][r] * ivr);
  }
}

// ---------------- launch ----------------
extern "C" void kernel_launch(void* const* d_in, const int* in_sizes, int n_in,
                              void* d_out, int out_size, void* d_ws, size_t ws_size,
                              hipStream_t stream) {
  const float* x      = (const float*)d_in[0];
  // d_in[1] = mask (derived analytically; unused)
  const float* cosT   = (const float*)d_in[2];
  const float* sinT   = (const float*)d_in[3];
  const int*   sp     = (const int*)d_in[4];
  const float* prev_k = (const float*)d_in[5];
  const float* prev_v = (const float*)d_in[6];
  const float* q_w    = (const float*)d_in[7];
  const float* k_w    = (const float*)d_in[8];
  const float* v_w    = (const float*)d_in[9];
  const float* o_w    = (const float*)d_in[10];

  float* out   = (float*)d_out;
  float* k_all = out + (size_t)B_ * T_ * H_ * HD_;      // +8388608
  float* v_all = k_all + (size_t)B_ * G_ * S_ * HD_;    // +16777216

  char* w = (char*)d_ws;
  u16* wt_qkv = (u16*)(w);                 // [6144][4096] bf16   50331648 B
  u16* wt_o   = (u16*)(w + 50331648);      // [4096][4096] bf16   33554432 B
  u16* x_bf   = (u16*)(w + 83886080);      // [2048][4096] bf16   16777216 B
  u16* qkv_bf = (u16*)(w + 100663296);     // [2048][6144] bf16   25165824 B
  u16* q_rope = (u16*)(w + 125829120);     // [4][32][512][128]   16777216 B
  u16* k_bf   = (u16*)(w + 142606336);     // [4][8][4096][128]   33554432 B
  u16* v_t    = (u16*)(w + 176160768);     // [4][8][128][4096]   33554432 B
  u16* ctx    = (u16*)(w + 209715200);     // [2048][4096]        16777216 B
  if (ws_size < 226492416ull) return;      // workspace too small -> bench will flag it

  k_cvt_x<<<8192, 256, 0, stream>>>(x, x_bf);
  k_twt<<<dim3(64, 64), 256, 0, stream>>>(q_w, 4096, wt_qkv);
  k_twt<<<dim3(64, 16), 256, 0, stream>>>(k_w, 1024, wt_qkv + (size_t)4096 * 4096);
  k_twt<<<dim3(64, 16), 256, 0, stream>>>(v_w, 1024, wt_qkv + (size_t)5120 * 4096);
  k_twt<<<dim3(64, 64), 256, 0, stream>>>(o_w, 4096, wt_o);
  k_prep_k<<<dim3(448, 32), 256, 0, stream>>>(prev_k, k_all, k_bf);
  k_prep_v<<<dim3(56, 32), 256, 0, stream>>>(prev_v, v_all, v_t);
  k_gemm2<256, false><<<192, 512, 0, stream>>>(x_bf, wt_qkv, qkv_bf, M_, NQKV, 4096);
  k_rope<<<2048, 256, 0, stream>>>(qkv_bf, cosT, sinT, sp, q_rope, k_bf, k_all, v_all);
  k_tv_new<<<dim3(16, 32), 256, 0, stream>>>(qkv_bf, v_t);
  k_attn<<<256, 512, 0, stream>>>(q_rope, k_bf, v_t, sp, ctx);
  k_gemm2<128, true><<<256, 512, 0, stream>>>(ctx, wt_o, out, M_, 4096, 4096);
}

// Round 11
// 527.032 us; speedup vs baseline: 1.0435x; 1.0435x over previous
//
#include <hip/hip_runtime.h>

// ---------------- problem constants ----------------
#define B_     4
#define T_     512
#define DIN    4096
#define H_     32
#define G_     8
#define HD_    128
#define S_     4096
#define CACHE_ 3584
#define M_     2048          // B*T
#define NQKV   6144          // H*HD + 2*G*HD
#define SCALE  0.08838834764831843f  // 1/sqrt(128)
#define LOG2E  1.4426950408889634f
#define QSC    (SCALE * LOG2E)       // folded into Q at rope time -> softmax in exp2 domain

typedef __attribute__((ext_vector_type(4)))  float  f32x4;
typedef __attribute__((ext_vector_type(16))) float  f32x16;
typedef __attribute__((ext_vector_type(8)))  short  s16x8;   // 8 bf16 (4 VGPRs) MFMA frag
typedef __attribute__((ext_vector_type(4)))  unsigned short u16x4;
typedef __attribute__((ext_vector_type(8)))  unsigned short u16x8;
typedef __attribute__((ext_vector_type(4)))  unsigned int   u32x4;
typedef unsigned short u16;
typedef unsigned int   u32;

__device__ __forceinline__ u16 f2bf(float f) {
  u32 u = __builtin_bit_cast(u32, f);
  return (u16)((u + 0x7fffu + ((u >> 16) & 1u)) >> 16);   // RNE
}
__device__ __forceinline__ float bf2f(u16 h) {
  return __builtin_bit_cast(float, (u32)h << 16);
}
__device__ __forceinline__ f32x4 mfma16(s16x8 a, s16x8 b, f32x4 c) {
  return __builtin_amdgcn_mfma_f32_16x16x32_bf16(a, b, c, 0, 0, 0);
}
__device__ __forceinline__ u32 pkbf(float a, float b) {   // pack 2 f32 -> 2 bf16 (RNE)
  u32 r; asm("v_cvt_pk_bf16_f32 %0, %1, %2" : "=v"(r) : "v"(a), "v"(b)); return r;
}
// async global->LDS, 16B per lane; LDS dest is wave-uniform base + lane*16
__device__ __forceinline__ void gload_lds16(const void* g, void* l) {
  __builtin_amdgcn_global_load_lds((__attribute__((address_space(1))) void*)g,
                                   (__attribute__((address_space(3))) void*)l, 16, 0, 0);
}

// ---------------- merged prep: x f32->bf16 + 4 weight transposes ----------------
// grid (64, 288): by<64 q_w | by<80 k_w | by<96 v_w | by<160 o_w | by>=160 cvt_x
__global__ __launch_bounds__(256) void k_prep_w(const float* __restrict__ qw, const float* __restrict__ kw,
                                                const float* __restrict__ vw, const float* __restrict__ ow,
                                                const float* __restrict__ x,
                                                u16* __restrict__ wt_qkv, u16* __restrict__ wt_o,
                                                u16* __restrict__ xb) {
  const int bx = blockIdx.x, by = blockIdx.y, t = threadIdx.x;
  if (by >= 160) {   // cvt_x: 8192 linear blocks
    size_t i = (((size_t)(by - 160) * 64 + bx) * 256 + t) * 4;
    f32x4 v = *(const f32x4*)(x + i);
    u16x4 o = { f2bf(v[0]), f2bf(v[1]), f2bf(v[2]), f2bf(v[3]) };
    *(u16x4*)(xb + i) = o;
    return;
  }
  __shared__ float tile[64][68];
  const float* src; u16* dst; int ldn, n0;
  if (by < 64)      { src = qw; ldn = 4096; dst = wt_qkv;                         n0 = by * 64; }
  else if (by < 80) { src = kw; ldn = 1024; dst = wt_qkv + (size_t)4096 * 4096;   n0 = (by - 64) * 64; }
  else if (by < 96) { src = vw; ldn = 1024; dst = wt_qkv + (size_t)5120 * 4096;   n0 = (by - 80) * 64; }
  else              { src = ow; ldn = 4096; dst = wt_o;                           n0 = (by - 96) * 64; }
  const int k0 = bx * 64;
  int rr = t >> 4, cc = (t & 15) * 4;
#pragma unroll
  for (int p = 0; p < 4; ++p) {
    int r = p * 16 + rr;
    f32x4 v = *(const f32x4*)(src + (size_t)(k0 + r) * ldn + n0 + cc);
    tile[r][cc] = v[0]; tile[r][cc + 1] = v[1]; tile[r][cc + 2] = v[2]; tile[r][cc + 3] = v[3];
  }
  __syncthreads();
#pragma unroll
  for (int p = 0; p < 4; ++p) {
    int n = p * 16 + rr;
    u16x4 o = { f2bf(tile[cc][n]), f2bf(tile[cc + 1][n]), f2bf(tile[cc + 2][n]), f2bf(tile[cc + 3][n]) };
    *(u16x4*)(dst + (size_t)(n0 + n) * 4096 + k0 + cc) = o;
  }
}

// ---------------- merged prep: prev_k copy+bf16 / prev_v copy+transposed bf16 ----------------
// grid (504, 32): bx<448 -> prep_k; bx>=448 -> prep_v (s0=(bx-448)*64)
__global__ __launch_bounds__(256) void k_prep_kv(const float* __restrict__ pk, const float* __restrict__ pv,
                                                 float* __restrict__ k_all, float* __restrict__ v_all,
                                                 u16* __restrict__ kb, u16* __restrict__ vt) {
  __shared__ float tile[64][132];
  const int bg = blockIdx.y, t = threadIdx.x;
  if (blockIdx.x < 448) {
    size_t si = ((size_t)blockIdx.x * 256 + t) * 4;   // < 3584*128
    f32x4 v = *(const f32x4*)(pk + (size_t)bg * CACHE_ * HD_ + si);
    size_t dof = (size_t)bg * S_ * HD_ + si;
    *(f32x4*)(k_all + dof) = v;
    u16x4 o = { f2bf(v[0]), f2bf(v[1]), f2bf(v[2]), f2bf(v[3]) };
    *(u16x4*)(kb + dof) = o;
    return;
  }
  const int s0 = (blockIdx.x - 448) * 64;
  const float* src = pv + ((size_t)bg * CACHE_ + s0) * HD_;
  float* dc = v_all + ((size_t)bg * S_ + s0) * HD_;
  int r8 = t >> 5, c4 = (t & 31) * 4;
#pragma unroll
  for (int p = 0; p < 8; ++p) {
    int r = p * 8 + r8;
    f32x4 v = *(const f32x4*)(src + (size_t)r * HD_ + c4);
    *(f32x4*)(dc + (size_t)r * HD_ + c4) = v;
    tile[r][c4] = v[0]; tile[r][c4 + 1] = v[1]; tile[r][c4 + 2] = v[2]; tile[r][c4 + 3] = v[3];
  }
  __syncthreads();
  int hr = t >> 4, s4 = (t & 15) * 4;
#pragma unroll
  for (int p = 0; p < 8; ++p) {
    int hd = p * 16 + hr;
    u16x4 o = { f2bf(tile[s4][hd]), f2bf(tile[s4 + 1][hd]), f2bf(tile[s4 + 2][hd]), f2bf(tile[s4 + 3][hd]) };
    *(u16x4*)(vt + ((size_t)bg * HD_ + hd) * S_ + s0 + s4) = o;
  }
}

// ---------------- GEMM v2: C[M][N] = A[M][K]bf16 @ Bt[N][K]bf16 ----------------
template<int BM, bool OUT_F32>
__global__ __launch_bounds__(512, 1) void k_gemm2(const u16* __restrict__ A, const u16* __restrict__ Bt,
                                                  void* __restrict__ Cp, int M, int N, int K) {
  constexpr int MI = BM / 32;        // A-frag repeats per wave (8 or 4)
  constexpr int LA = BM / 64;        // A stage loads/thread per K-tile (4 or 2)
  __shared__ u16 As[2 * BM * 64];    // [buf][BM][64], chunk16 ch' = ch ^ (row&7)
  __shared__ u16 Bs[2 * 256 * 64];
  const int tid = threadIdx.x, w = tid >> 6, lane = tid & 63;
  const int wr = w >> 2, wc = w & 3;             // wave tile: rows wr*(BM/2), cols wc*64
  const int cl = lane & 15, khi = lane >> 4;
  // --- T1: bijective XCD swizzle, column-major (bm fast) ---
  const int Mt = M / BM;
  const int nwg = gridDim.x;
  const int q = nwg >> 3, r8 = nwg & 7;
  const int xcd = blockIdx.x & 7, pos = blockIdx.x >> 3;
  const int wgid = (xcd < r8 ? xcd * (q + 1) : r8 * (q + 1) + (xcd - r8) * q) + pos;
  const int m0 = (wgid % Mt) * BM, n0 = (wgid / Mt) * 256;
  // --- staging addresses (inverse-swizzled global source) ---
  const int rb = tid >> 3;                       // 0..63
  const int csw = ((tid & 7) ^ (rb & 7)) * 8;    // element offset, pre-swizzled
  const u16* aS = A  + (size_t)(m0 + rb) * K + csw;
  const u16* bS = Bt + (size_t)(n0 + rb) * K + csw;
  u16* aD = As + w * 512;                        // + buf*BM*64 + i*4096; lane*16B implicit
  u16* bD = Bs + w * 512;
  // --- swizzled read chunk offsets (row&7 == cl&7 for all frags) ---
  const int ck0 = ((0 + khi) ^ (cl & 7)) * 8;
  const int ck1 = ((4 + khi) ^ (cl & 7)) * 8;
  const int NT = K >> 6;
  f32x4 acc[MI][4] = {};

#define STAGE_(buf, tt)                                                                   \
  do {                                                                                    \
    _Pragma("unroll")                                                                     \
    for (int i = 0; i < LA; ++i)                                                          \
      gload_lds16(aS + (size_t)(i * 64) * K + (size_t)(tt) * 64, aD + (buf) * (BM * 64) + i * 4096); \
    _Pragma("unroll")                                                                     \
    for (int i = 0; i < 4; ++i)                                                           \
      gload_lds16(bS + (size_t)(i * 64) * K + (size_t)(tt) * 64, bD + (buf) * (256 * 64) + i * 4096); \
  } while (0)
#define VMCNT_L_()                                                                        \
  do {                                                                                    \
    if constexpr (BM == 256) asm volatile("s_waitcnt vmcnt(8)" ::: "memory");             \
    else                     asm volatile("s_waitcnt vmcnt(6)" ::: "memory");             \
  } while (0)

  STAGE_(0, 0);
  STAGE_(1, 1);
  VMCNT_L_();
  __builtin_amdgcn_sched_barrier(0);
  __builtin_amdgcn_s_barrier();
  __builtin_amdgcn_sched_barrier(0);

  for (int t = 0; t < NT; ++t) {
    const int buf = t & 1;
    const int ab = buf * (BM * 64) + (wr * (BM / 2) + cl) * 64;
    const int bb = buf * (256 * 64) + (wc * 64 + cl) * 64;
#pragma unroll
    for (int kk = 0; kk < 2; ++kk) {
      const int ck = kk ? ck1 : ck0;
      s16x8 bf4[4], af[MI];
#pragma unroll
      for (int ni = 0; ni < 4; ++ni) bf4[ni] = *(const s16x8*)(Bs + bb + ni * 16 * 64 + ck);
#pragma unroll
      for (int mi = 0; mi < MI; ++mi) af[mi] = *(const s16x8*)(As + ab + mi * 16 * 64 + ck);
      __builtin_amdgcn_s_setprio(1);
#pragma unroll
      for (int mi = 0; mi < MI; ++mi)
#pragma unroll
        for (int ni = 0; ni < 4; ++ni)
          acc[mi][ni] = mfma16(af[mi], bf4[ni], acc[mi][ni]);
      __builtin_amdgcn_s_setprio(0);
    }
    __builtin_amdgcn_sched_barrier(0);
    __builtin_amdgcn_s_barrier();     // all waves done reading buf (ds data already retired pre-MFMA)
    __builtin_amdgcn_sched_barrier(0);
    if (t + 2 < NT) STAGE_(buf, t + 2);
    VMCNT_L_();                       // tile t+1 landed; t+2's loads stay in flight (T4)
    __builtin_amdgcn_sched_barrier(0);
    __builtin_amdgcn_s_barrier();
    __builtin_amdgcn_sched_barrier(0);
  }
#undef STAGE_
#undef VMCNT_L_
  const int rl = khi * 4;
#pragma unroll
  for (int mi = 0; mi < MI; ++mi)
#pragma unroll
    for (int ni = 0; ni < 4; ++ni) {
      int col = n0 + wc * 64 + ni * 16 + cl;
#pragma unroll
      for (int r = 0; r < 4; ++r) {
        int rw = m0 + wr * (BM / 2) + mi * 16 + rl + r;
        if (OUT_F32) ((float*)Cp)[(size_t)rw * N + col] = acc[mi][ni][r];
        else         ((u16*)Cp)[(size_t)rw * N + col]   = f2bf(acc[mi][ni][r]);
      }
    }
}

// ---------------- RoPE + scatter (Q pre-scaled by SCALE*log2e for exp2-domain softmax) ----------------
__global__ __launch_bounds__(256) void k_rope(const u16* __restrict__ qkv, const float* __restrict__ cosT,
                                              const float* __restrict__ sinT, const int* __restrict__ sp,
                                              u16* __restrict__ qr, u16* __restrict__ kb,
                                              float* __restrict__ k_all, float* __restrict__ v_all) {
  int bt = blockIdx.x;
  int b = bt >> 9, t = bt & 511;
  int pos = sp[b] + t;
  const u16* row = qkv + (size_t)bt * NQKV;
  for (int idx = threadIdx.x; idx < 2560; idx += 256) {   // 40 roped heads * 64 pairs
    int head = idx >> 6, d = idx & 63;
    float c = cosT[pos * HD_ + d], s = sinT[pos * HD_ + d];
    float x1 = bf2f(row[head * HD_ + d]);
    float x2 = bf2f(row[head * HD_ + d + 64]);
    float y1 = x1 * c - x2 * s;
    float y2 = x2 * c + x1 * s;
    if (head < 32) {
      size_t o = (((size_t)b * H_ + head) * T_ + t) * HD_ + d;
      qr[o] = f2bf(y1 * QSC); qr[o + 64] = f2bf(y2 * QSC);
    } else {
      int g = head - 32;
      size_t o = (((size_t)b * G_ + g) * S_ + CACHE_ + t) * HD_ + d;
      kb[o] = f2bf(y1); kb[o + 64] = f2bf(y2);
      k_all[o] = y1; k_all[o + 64] = y2;
    }
  }
  for (int idx = threadIdx.x; idx < 1024; idx += 256) {   // v passthrough (f32 copy only)
    int g = idx >> 7;
    float v = bf2f(row[5120 + idx]);
    size_t o = (((size_t)b * G_ + g) * S_ + CACHE_ + t) * HD_ + (idx & 127);
    v_all[o] = v;
  }
}

// ---------------- transpose new-V slice into v_t[bg][hd][CACHE_..S] ----------------
__global__ __launch_bounds__(256) void k_tv_new(const u16* __restrict__ qkv, u16* __restrict__ vt) {
  __shared__ u16 tile[64][72];
  int bg = blockIdx.y;
  int b = bg >> 3, g = bg & 7;
  int tt = blockIdx.x >> 1, ht = blockIdx.x & 1;
  int t0 = tt * 64, hd0 = ht * 64;
  int t = threadIdx.x;
  int rr = t >> 3, c8 = (t & 7) * 8;
#pragma unroll
  for (int p = 0; p < 2; ++p) {
    int r = p * 32 + rr;
    *(u16x8*)(&tile[r][c8]) =
      *(const u16x8*)(qkv + (size_t)(b * T_ + t0 + r) * NQKV + 5120 + g * HD_ + hd0 + c8);
  }
  __syncthreads();
  int hr = t >> 4, s4 = (t & 15) * 4;
#pragma unroll
  for (int p = 0; p < 4; ++p) {
    int hd = p * 16 + hr;
    u16x4 o = { tile[s4][hd], tile[s4 + 1][hd], tile[s4 + 2][hd], tile[s4 + 3][hd] };
    *(u16x4*)(vt + ((size_t)bg * HD_ + hd0 + hd) * S_ + CACHE_ + t0 + s4) = o;
  }
}

// ---------------- flash attention v8: R7 proven structure (shfl_xor cross-lane) ----------------
// 8 waves x 32 q (256 q/block), grid 256 = 1 block/CU, XCD-grouped KV slabs, dbuf LDS
// single-barrier pipeline, max3 tree, 8-partial row-sum. Cross-lane via __shfl_xor —
// permlane32_swap reverted (R9/R10: on-HW pack semantics mismatch; probe before reuse).
__global__ __launch_bounds__(512) void k_attn(const u16* __restrict__ Q, const u16* __restrict__ Kc,
                                              const u16* __restrict__ Vt, const int* __restrict__ sp,
                                              u16* __restrict__ ctx) {
  __shared__ u16 Ks[2][64 * 128];   // [buf][kv64][16 chunks16B], chunk c at c ^ (row&15)
  __shared__ u16 Vs[2][128 * 64];   // [buf][hd128][8 chunks16B], chunk c at c ^ (row&7)
  const int xcd = blockIdx.x & 7, pos = blockIdx.x >> 3;
  const int wgid = xcd * 32 + pos;                 // nwg = 256; 8 consecutive share one (b,g)
  const int qh = wgid & 1, hq = (wgid >> 1) & 3, bg = wgid >> 3;
  const int b = bg >> 3, g = bg & 7, h = g * 4 + hq;
  const int tid = threadIdx.x, w = tid >> 6, lane = tid & 63;
  const int l31 = lane & 31, hh = lane >> 5;
  const int cache = sp[b];
  const int qbase = qh * 256;
  const int qtok = qbase + w * 32 + l31;           // this lane's softmax q-row
  const size_t kvoff = (size_t)bg * S_ * HD_;
  const u16* kp = Kc + kvoff;
  const u16* vp = Vt + kvoff;
  s16x8 qreg[8];
  {
    const u16* qb = Q + ((size_t)(b * H_ + h) * T_ + qtok) * HD_;
#pragma unroll
    for (int s = 0; s < 8; ++s) qreg[s] = *(const s16x8*)(qb + s * 16 + hh * 8);
  }
  f32x16 acc[4] = {};
  float mr = -1e30f, ls = 0.f;
  const int krow = w * 8 + (lane >> 3), kch = lane & 7;
  const int vrow = w * 16 + (lane >> 2), vch = lane & 3;
  const int kswz = (krow & 15) << 3;               // element offsets
  const int vswz = (vrow & 7) << 3;
  const int rdswzK = (l31 & 15) << 3;
  const int rdswzV = (l31 & 7) << 3;
  const int jm = (cache + qbase + w * 32) >> 6;    // first tile needing mask (per wave)
  const int jlastB = (cache + qbase + 255) >> 6;   // block-uniform loop bound
  const int kvlim = cache + qtok;
  u16x8 rk0, rk1, rv0, rv1;
  // prologue: tile 0 -> regs -> buf0; prefetch tile 1 -> regs
  rk0 = *(const u16x8*)(kp + (size_t)krow * HD_ + kch * 8);
  rk1 = *(const u16x8*)(kp + (size_t)krow * HD_ + (kch + 8) * 8);
  rv0 = *(const u16x8*)(vp + (size_t)vrow * S_ + vch * 8);
  rv1 = *(const u16x8*)(vp + (size_t)vrow * S_ + (vch + 4) * 8);
  *(u16x8*)(Ks[0] + krow * 128 + ((kch * 8) ^ kswz))       = rk0;
  *(u16x8*)(Ks[0] + krow * 128 + (((kch + 8) * 8) ^ kswz)) = rk1;
  *(u16x8*)(Vs[0] + vrow * 64 + ((vch * 8) ^ vswz))        = rv0;
  *(u16x8*)(Vs[0] + vrow * 64 + (((vch + 4) * 8) ^ vswz))  = rv1;
  rk0 = *(const u16x8*)(kp + (size_t)(64 + krow) * HD_ + kch * 8);
  rk1 = *(const u16x8*)(kp + (size_t)(64 + krow) * HD_ + (kch + 8) * 8);
  rv0 = *(const u16x8*)(vp + (size_t)vrow * S_ + 64 + vch * 8);
  rv1 = *(const u16x8*)(vp + (size_t)vrow * S_ + 64 + (vch + 4) * 8);
  __syncthreads();
  for (int j = 0; j <= jlastB; ++j) {
    const int buf = j & 1;
    const u16* KsB = Ks[buf];
    const u16* VsB = Vs[buf];
    u16* Ksn = Ks[buf ^ 1];
    u16* Vsn = Vs[buf ^ 1];
    // (1) QK issue: S^T[kv][q] = K-tile @ Q^T (2 kv-blocks of 32)
    f32x16 sa[2] = {};
    __builtin_amdgcn_s_setprio(1);
#pragma unroll
    for (int s = 0; s < 8; ++s) {
      s16x8 ka = *(const s16x8*)(KsB + l31 * 128 + ((s * 16 + hh * 8) ^ rdswzK));
      sa[0] = __builtin_amdgcn_mfma_f32_32x32x16_bf16(ka, qreg[s], sa[0], 0, 0, 0);
    }
#pragma unroll
    for (int s = 0; s < 8; ++s) {
      s16x8 ka = *(const s16x8*)(KsB + (32 + l31) * 128 + ((s * 16 + hh * 8) ^ rdswzK));
      sa[1] = __builtin_amdgcn_mfma_f32_32x32x16_bf16(ka, qreg[s], sa[1], 0, 0, 0);
    }
    __builtin_amdgcn_s_setprio(0);
    // (2) stage tile j+1 into buf^1 (its last readers finished before the previous barrier)
    if (j < jlastB) {
      *(u16x8*)(Ksn + krow * 128 + ((kch * 8) ^ kswz))       = rk0;
      *(u16x8*)(Ksn + krow * 128 + (((kch + 8) * 8) ^ kswz)) = rk1;
      *(u16x8*)(Vsn + vrow * 64 + ((vch * 8) ^ vswz))        = rv0;
      *(u16x8*)(Vsn + vrow * 64 + (((vch + 4) * 8) ^ vswz))  = rv1;
    }
    // (3) prefetch tile j+2 -> regs (in flight across softmax+PV)
    if (j + 2 <= jlastB) {
      rk0 = *(const u16x8*)(kp + (size_t)((j + 2) * 64 + krow) * HD_ + kch * 8);
      rk1 = *(const u16x8*)(kp + (size_t)((j + 2) * 64 + krow) * HD_ + (kch + 8) * 8);
      rv0 = *(const u16x8*)(vp + (size_t)vrow * S_ + (j + 2) * 64 + vch * 8);
      rv1 = *(const u16x8*)(vp + (size_t)vrow * S_ + (j + 2) * 64 + (vch + 4) * 8);
    }
    // (4) softmax
    if (j >= jm) {   // causal mask: only tiles >= jm can have masked kv
#pragma unroll
      for (int r = 0; r < 16; ++r) {
        int kv = j * 64 + (r & 3) + 8 * (r >> 2) + 4 * hh;
        if (kv > kvlim)      sa[0][r] = -1e30f;
        if (kv + 32 > kvlim) sa[1][r] = -1e30f;
      }
    }
    // row max: max3 tree (T17) + shfl lane^32 exchange (proven R7 form)
    float mx;
    {
      float t[16];
#pragma unroll
      for (int r = 0; r < 16; ++r) t[r] = fmaxf(sa[0][r], sa[1][r]);
#define F3_(a, b, c) fmaxf(fmaxf(a, b), c)
      float u0 = F3_(t[0], t[1], t[2]);
      float u1 = F3_(t[3], t[4], t[5]);
      float u2 = F3_(t[6], t[7], t[8]);
      float u3 = F3_(t[9], t[10], t[11]);
      float u4 = F3_(t[12], t[13], t[14]);
      float lm = fmaxf(F3_(u0, u1, u2), F3_(u3, u4, t[15]));
#undef F3_
      mx = fmaxf(lm, __shfl_xor(lm, 32));
    }
    // defer-max (T13): rescale only when max grew > 8 (exp2 domain)
    if (__any(mx > mr + 8.f)) {
      float nm = fmaxf(mr, mx);
      float al = __builtin_amdgcn_exp2f(mr - nm);
      mr = nm; ls *= al;
#pragma unroll
      for (int r = 0; r < 16; ++r) {
        float ar = __shfl(al, (r & 3) + 8 * (r >> 2) + 4 * hh, 64);
        acc[0][r] *= ar; acc[1][r] *= ar; acc[2][r] *= ar; acc[3][r] *= ar;
      }
    }
    // exp2 + row sum with 8 parallel partials (breaks the serial add chain)
    float p0 = 0.f, p1 = 0.f, p2 = 0.f, p3 = 0.f, p4 = 0.f, p5 = 0.f, p6 = 0.f, p7 = 0.f;
#pragma unroll
    for (int r = 0; r < 16; r += 4) {
      float e0 = __builtin_amdgcn_exp2f(sa[0][r]     - mr);
      float e1 = __builtin_amdgcn_exp2f(sa[0][r + 1] - mr);
      float e2 = __builtin_amdgcn_exp2f(sa[0][r + 2] - mr);
      float e3 = __builtin_amdgcn_exp2f(sa[0][r + 3] - mr);
      sa[0][r] = e0; sa[0][r + 1] = e1; sa[0][r + 2] = e2; sa[0][r + 3] = e3;
      p0 += e0; p1 += e1; p2 += e2; p3 += e3;
    }
#pragma unroll
    for (int r = 0; r < 16; r += 4) {
      float e0 = __builtin_amdgcn_exp2f(sa[1][r]     - mr);
      float e1 = __builtin_amdgcn_exp2f(sa[1][r + 1] - mr);
      float e2 = __builtin_amdgcn_exp2f(sa[1][r + 2] - mr);
      float e3 = __builtin_amdgcn_exp2f(sa[1][r + 3] - mr);
      sa[1][r] = e0; sa[1][r + 1] = e1; sa[1][r + 2] = e2; sa[1][r + 3] = e3;
      p4 += e0; p5 += e1; p6 += e2; p7 += e3;
    }
    float rsum = ((p0 + p1) + (p2 + p3)) + ((p4 + p5) + (p6 + p7));
    ls += rsum + __shfl_xor(rsum, 32);
    // pack P (D-layout) into 4 MFMA A-frags (proven R7 form: shfl_xor + select)
    s16x8 pf[4];
#pragma unroll
    for (int sb = 0; sb < 2; ++sb) {
      u32 a0 = pkbf(sa[sb][0],  sa[sb][1]),  a1 = pkbf(sa[sb][2],  sa[sb][3]);
      u32 b0 = pkbf(sa[sb][4],  sa[sb][5]),  b1 = pkbf(sa[sb][6],  sa[sb][7]);
      u32 c0 = pkbf(sa[sb][8],  sa[sb][9]),  c1 = pkbf(sa[sb][10], sa[sb][11]);
      u32 d0 = pkbf(sa[sb][12], sa[sb][13]), d1 = pkbf(sa[sb][14], sa[sb][15]);
      u32 xa0 = __shfl_xor(a0, 32), xa1 = __shfl_xor(a1, 32);
      u32 xb0 = __shfl_xor(b0, 32), xb1 = __shfl_xor(b1, 32);
      u32 xc0 = __shfl_xor(c0, 32), xc1 = __shfl_xor(c1, 32);
      u32 xd0 = __shfl_xor(d0, 32), xd1 = __shfl_xor(d1, 32);
      u32x4 f0 = { hh ? xb0 : a0, hh ? xb1 : a1, hh ? b0 : xa0, hh ? b1 : xa1 };
      u32x4 f1 = { hh ? xd0 : c0, hh ? xd1 : c1, hh ? d0 : xc0, hh ? d1 : xc1 };
      pf[sb * 2]     = __builtin_bit_cast(s16x8, f0);
      pf[sb * 2 + 1] = __builtin_bit_cast(s16x8, f1);
    }
    // (5) O += P V  (B-frags straight from swizzled Vs)
    __builtin_amdgcn_s_setprio(1);
#pragma unroll
    for (int hb = 0; hb < 4; ++hb) {
      const int vro = hb * 32 + l31;
#pragma unroll
      for (int kb = 0; kb < 4; ++kb) {
        s16x8 vb = *(const s16x8*)(VsB + vro * 64 + ((kb * 16 + hh * 8) ^ rdswzV));
        acc[hb] = __builtin_amdgcn_mfma_f32_32x32x16_bf16(pf[kb], vb, acc[hb], 0, 0, 0);
      }
    }
    __builtin_amdgcn_s_setprio(0);
    // (6) single barrier: publishes buf^1 (tile j+1), retires all reads of buf (tile j)
    __syncthreads();
  }
  // epilogue: normalize rows (ls lives at lane l31==row) and store ctx
  float inv = 1.0f / ls;
#pragma unroll
  for (int r = 0; r < 16; ++r) {
    int ql = (r & 3) + 8 * (r >> 2) + 4 * hh;
    float ivr = __shfl(inv, ql, 64);
    u16* cb = ctx + ((size_t)(b * T_ + qbase + w * 32 + ql)) * 4096 + h * HD_ + l31;
    cb[0]  = f2bf(acc[0][r] * ivr);
    cb[32] = f2bf(acc[1][r] * ivr);
    cb[64] = f2bf(acc[2][r] * ivr);
    cb[96] = f2bf(acc[3][r] * ivr);
  }
}

// ---------------- launch ----------------
extern "C" void kernel_launch(void* const* d_in, const int* in_sizes, int n_in,
                              void* d_out, int out_size, void* d_ws, size_t ws_size,
                              hipStream_t stream) {
  const float* x      = (const float*)d_in[0];
  // d_in[1] = mask (derived analytically; unused)
  const float* cosT   = (const float*)d_in[2];
  const float* sinT   = (const float*)d_in[3];
  const int*   sp     = (const int*)d_in[4];
  const float* prev_k = (const float*)d_in[5];
  const float* prev_v = (const float*)d_in[6];
  const float* q_w    = (const float*)d_in[7];
  const float* k_w    = (const float*)d_in[8];
  const float* v_w    = (const float*)d_in[9];
  const float* o_w    = (const float*)d_in[10];

  float* out   = (float*)d_out;
  float* k_all = out + (size_t)B_ * T_ * H_ * HD_;      // +8388608
  float* v_all = k_all + (size_t)B_ * G_ * S_ * HD_;    // +16777216

  char* w = (char*)d_ws;
  u16* wt_qkv = (u16*)(w);                 // [6144][4096] bf16   50331648 B
  u16* wt_o   = (u16*)(w + 50331648);      // [4096][4096] bf16   33554432 B
  u16* x_bf   = (u16*)(w + 83886080);      // [2048][4096] bf16   16777216 B
  u16* qkv_bf = (u16*)(w + 100663296);     // [2048][6144] bf16   25165824 B
  u16* q_rope = (u16*)(w + 125829120);     // [4][32][512][128]   16777216 B
  u16* k_bf   = (u16*)(w + 142606336);     // [4][8][4096][128]   33554432 B
  u16* v_t    = (u16*)(w + 176160768);     // [4][8][128][4096]   33554432 B
  u16* ctx    = (u16*)(w + 209715200);     // [2048][4096]        16777216 B
  if (ws_size < 226492416ull) return;      // workspace too small -> bench will flag it

  k_prep_w<<<dim3(64, 288), 256, 0, stream>>>(q_w, k_w, v_w, o_w, x, wt_qkv, wt_o, x_bf);
  k_prep_kv<<<dim3(504, 32), 256, 0, stream>>>(prev_k, prev_v, k_all, v_all, k_bf, v_t);
  k_gemm2<256, false><<<192, 512, 0, stream>>>(x_bf, wt_qkv, qkv_bf, M_, NQKV, 4096);
  k_rope<<<2048, 256, 0, stream>>>(qkv_bf, cosT, sinT, sp, q_rope, k_bf, k_all, v_all);
  k_tv_new<<<dim3(16, 32), 256, 0, stream>>>(qkv_bf, v_t);
  k_attn<<<256, 512, 0, stream>>>(q_rope, k_bf, v_t, sp, ctx);
  k_gemm2<128, true><<<256, 512, 0, stream>>>(ctx, wt_o, out, M_, 4096, 4096);
}

// Round 12
// 508.180 us; speedup vs baseline: 1.0822x; 1.0371x over previous
//
#include <hip/hip_runtime.h>

// ---------------- problem constants ----------------
#define B_     4
#define T_     512
#define DIN    4096
#define H_     32
#define G_     8
#define HD_    128
#define S_     4096
#define CACHE_ 3584
#define M_     2048          // B*T
#define NQKV   6144          // H*HD + 2*G*HD
#define SCALE  0.08838834764831843f  // 1/sqrt(128)
#define LOG2E  1.4426950408889634f
#define QSC    (SCALE * LOG2E)       // folded into Q at rope time -> softmax in exp2 domain

typedef __attribute__((ext_vector_type(4)))  float  f32x4;
typedef __attribute__((ext_vector_type(16))) float  f32x16;
typedef __attribute__((ext_vector_type(8)))  short  s16x8;   // 8 bf16 (4 VGPRs) MFMA frag
typedef __attribute__((ext_vector_type(4)))  unsigned short u16x4;
typedef __attribute__((ext_vector_type(8)))  unsigned short u16x8;
typedef __attribute__((ext_vector_type(4)))  unsigned int   u32x4;
typedef unsigned short u16;
typedef unsigned int   u32;

__device__ __forceinline__ u16 f2bf(float f) {
  u32 u = __builtin_bit_cast(u32, f);
  return (u16)((u + 0x7fffu + ((u >> 16) & 1u)) >> 16);   // RNE
}
__device__ __forceinline__ float bf2f(u16 h) {
  return __builtin_bit_cast(float, (u32)h << 16);
}
__device__ __forceinline__ f32x4 mfma16(s16x8 a, s16x8 b, f32x4 c) {
  return __builtin_amdgcn_mfma_f32_16x16x32_bf16(a, b, c, 0, 0, 0);
}
__device__ __forceinline__ u32 pkbf(float a, float b) {   // pack 2 f32 -> 2 bf16 (RNE)
  u32 r; asm("v_cvt_pk_bf16_f32 %0, %1, %2" : "=v"(r) : "v"(a), "v"(b)); return r;
}
// async global->LDS, 16B per lane; LDS dest is wave-uniform base + lane*16
__device__ __forceinline__ void gload_lds16(const void* g, void* l) {
  __builtin_amdgcn_global_load_lds((__attribute__((address_space(1))) void*)g,
                                   (__attribute__((address_space(3))) void*)l, 16, 0, 0);
}

// ---------------- merged prep: x f32->bf16 + 4 weight transposes ----------------
// grid (64, 288): by<64 q_w | by<80 k_w | by<96 v_w | by<160 o_w | by>=160 cvt_x
__global__ __launch_bounds__(256) void k_prep_w(const float* __restrict__ qw, const float* __restrict__ kw,
                                                const float* __restrict__ vw, const float* __restrict__ ow,
                                                const float* __restrict__ x,
                                                u16* __restrict__ wt_qkv, u16* __restrict__ wt_o,
                                                u16* __restrict__ xb) {
  const int bx = blockIdx.x, by = blockIdx.y, t = threadIdx.x;
  if (by >= 160) {   // cvt_x: 8192 linear blocks
    size_t i = (((size_t)(by - 160) * 64 + bx) * 256 + t) * 4;
    f32x4 v = *(const f32x4*)(x + i);
    u16x4 o = { f2bf(v[0]), f2bf(v[1]), f2bf(v[2]), f2bf(v[3]) };
    *(u16x4*)(xb + i) = o;
    return;
  }
  __shared__ float tile[64][68];
  const float* src; u16* dst; int ldn, n0;
  if (by < 64)      { src = qw; ldn = 4096; dst = wt_qkv;                         n0 = by * 64; }
  else if (by < 80) { src = kw; ldn = 1024; dst = wt_qkv + (size_t)4096 * 4096;   n0 = (by - 64) * 64; }
  else if (by < 96) { src = vw; ldn = 1024; dst = wt_qkv + (size_t)5120 * 4096;   n0 = (by - 80) * 64; }
  else              { src = ow; ldn = 4096; dst = wt_o;                           n0 = (by - 96) * 64; }
  const int k0 = bx * 64;
  int rr = t >> 4, cc = (t & 15) * 4;
#pragma unroll
  for (int p = 0; p < 4; ++p) {
    int r = p * 16 + rr;
    f32x4 v = *(const f32x4*)(src + (size_t)(k0 + r) * ldn + n0 + cc);
    tile[r][cc] = v[0]; tile[r][cc + 1] = v[1]; tile[r][cc + 2] = v[2]; tile[r][cc + 3] = v[3];
  }
  __syncthreads();
#pragma unroll
  for (int p = 0; p < 4; ++p) {
    int n = p * 16 + rr;
    u16x4 o = { f2bf(tile[cc][n]), f2bf(tile[cc + 1][n]), f2bf(tile[cc + 2][n]), f2bf(tile[cc + 3][n]) };
    *(u16x4*)(dst + (size_t)(n0 + n) * 4096 + k0 + cc) = o;
  }
}

// ---------------- merged prep: prev_k copy+bf16 / prev_v copy+transposed bf16 ----------------
// grid (504, 32): bx<448 -> prep_k; bx>=448 -> prep_v (s0=(bx-448)*64)
__global__ __launch_bounds__(256) void k_prep_kv(const float* __restrict__ pk, const float* __restrict__ pv,
                                                 float* __restrict__ k_all, float* __restrict__ v_all,
                                                 u16* __restrict__ kb, u16* __restrict__ vt) {
  __shared__ float tile[64][132];
  const int bg = blockIdx.y, t = threadIdx.x;
  if (blockIdx.x < 448) {
    size_t si = ((size_t)blockIdx.x * 256 + t) * 4;   // < 3584*128
    f32x4 v = *(const f32x4*)(pk + (size_t)bg * CACHE_ * HD_ + si);
    size_t dof = (size_t)bg * S_ * HD_ + si;
    *(f32x4*)(k_all + dof) = v;
    u16x4 o = { f2bf(v[0]), f2bf(v[1]), f2bf(v[2]), f2bf(v[3]) };
    *(u16x4*)(kb + dof) = o;
    return;
  }
  const int s0 = (blockIdx.x - 448) * 64;
  const float* src = pv + ((size_t)bg * CACHE_ + s0) * HD_;
  float* dc = v_all + ((size_t)bg * S_ + s0) * HD_;
  int r8 = t >> 5, c4 = (t & 31) * 4;
#pragma unroll
  for (int p = 0; p < 8; ++p) {
    int r = p * 8 + r8;
    f32x4 v = *(const f32x4*)(src + (size_t)r * HD_ + c4);
    *(f32x4*)(dc + (size_t)r * HD_ + c4) = v;
    tile[r][c4] = v[0]; tile[r][c4 + 1] = v[1]; tile[r][c4 + 2] = v[2]; tile[r][c4 + 3] = v[3];
  }
  __syncthreads();
  int hr = t >> 4, s4 = (t & 15) * 4;
#pragma unroll
  for (int p = 0; p < 8; ++p) {
    int hd = p * 16 + hr;
    u16x4 o = { f2bf(tile[s4][hd]), f2bf(tile[s4 + 1][hd]), f2bf(tile[s4 + 2][hd]), f2bf(tile[s4 + 3][hd]) };
    *(u16x4*)(vt + ((size_t)bg * HD_ + hd) * S_ + s0 + s4) = o;
  }
}

// ---------------- GEMM v3: C[M][N] = A[M][K]bf16 @ Bt[N][K]bf16 ----------------
// BMxBN tile (BN=192 for QKV -> grid 256 = 1 block/CU, full coverage), 512 threads
// (8 waves 2Mx4N), dbuf LDS, global_load_lds w16, counted vmcnt(LA+NI), setprio, XCD swizzle.
template<int BM, int BN, bool OUT_F32>
__global__ __launch_bounds__(512, 1) void k_gemm2(const u16* __restrict__ A, const u16* __restrict__ Bt,
                                                  void* __restrict__ Cp, int M, int N, int K) {
  constexpr int MI = BM / 32;        // A-frag repeats per wave (8 or 4)
  constexpr int NI = BN / 64;        // B-frag repeats per wave (3 or 4); per-wave N = BN/4
  constexpr int LA = BM / 64;        // A stage loads/thread per K-tile (4 or 2)
  constexpr int VM = LA + NI;        // counted vmcnt: one full tile's loads in flight
  __shared__ u16 As[2 * BM * 64];    // [buf][BM][64], chunk16 ch' = ch ^ (row&7)
  __shared__ u16 Bs[2 * BN * 64];
  const int tid = threadIdx.x, w = tid >> 6, lane = tid & 63;
  const int wr = w >> 2, wc = w & 3;             // wave tile: rows wr*(BM/2), cols wc*(BN/4)
  const int cl = lane & 15, khi = lane >> 4;
  // --- T1: bijective XCD swizzle, column-major (bm fast) ---
  const int Mt = M / BM;
  const int nwg = gridDim.x;
  const int q = nwg >> 3, r8 = nwg & 7;
  const int xcd = blockIdx.x & 7, pos = blockIdx.x >> 3;
  const int wgid = (xcd < r8 ? xcd * (q + 1) : r8 * (q + 1) + (xcd - r8) * q) + pos;
  const int m0 = (wgid % Mt) * BM, n0 = (wgid / Mt) * BN;
  // --- staging addresses (inverse-swizzled global source) ---
  const int rb = tid >> 3;                       // 0..63
  const int csw = ((tid & 7) ^ (rb & 7)) * 8;    // element offset, pre-swizzled
  const u16* aS = A  + (size_t)(m0 + rb) * K + csw;
  const u16* bS = Bt + (size_t)(n0 + rb) * K + csw;
  u16* aD = As + w * 512;                        // + buf*BM*64 + i*4096; lane*16B implicit
  u16* bD = Bs + w * 512;
  // --- swizzled read chunk offsets (row&7 == cl&7 for all frags; BN/4 % 8 == 0) ---
  const int ck0 = ((0 + khi) ^ (cl & 7)) * 8;
  const int ck1 = ((4 + khi) ^ (cl & 7)) * 8;
  const int NT = K >> 6;
  f32x4 acc[MI][NI] = {};

#define STAGE_(buf, tt)                                                                   \
  do {                                                                                    \
    _Pragma("unroll")                                                                     \
    for (int i = 0; i < LA; ++i)                                                          \
      gload_lds16(aS + (size_t)(i * 64) * K + (size_t)(tt) * 64, aD + (buf) * (BM * 64) + i * 4096); \
    _Pragma("unroll")                                                                     \
    for (int i = 0; i < NI; ++i)                                                          \
      gload_lds16(bS + (size_t)(i * 64) * K + (size_t)(tt) * 64, bD + (buf) * (BN * 64) + i * 4096); \
  } while (0)
#define VMCNT_L_()                                                                        \
  do {                                                                                    \
    if constexpr (VM == 8)      asm volatile("s_waitcnt vmcnt(8)" ::: "memory");          \
    else if constexpr (VM == 7) asm volatile("s_waitcnt vmcnt(7)" ::: "memory");          \
    else                        asm volatile("s_waitcnt vmcnt(6)" ::: "memory");          \
  } while (0)

  STAGE_(0, 0);
  STAGE_(1, 1);
  VMCNT_L_();
  __builtin_amdgcn_sched_barrier(0);
  __builtin_amdgcn_s_barrier();
  __builtin_amdgcn_sched_barrier(0);

  for (int t = 0; t < NT; ++t) {
    const int buf = t & 1;
    const int ab = buf * (BM * 64) + (wr * (BM / 2) + cl) * 64;
    const int bb = buf * (BN * 64) + (wc * (BN / 4) + cl) * 64;
#pragma unroll
    for (int kk = 0; kk < 2; ++kk) {
      const int ck = kk ? ck1 : ck0;
      s16x8 bf4[NI], af[MI];
#pragma unroll
      for (int ni = 0; ni < NI; ++ni) bf4[ni] = *(const s16x8*)(Bs + bb + ni * 16 * 64 + ck);
#pragma unroll
      for (int mi = 0; mi < MI; ++mi) af[mi] = *(const s16x8*)(As + ab + mi * 16 * 64 + ck);
      __builtin_amdgcn_s_setprio(1);
#pragma unroll
      for (int mi = 0; mi < MI; ++mi)
#pragma unroll
        for (int ni = 0; ni < NI; ++ni)
          acc[mi][ni] = mfma16(af[mi], bf4[ni], acc[mi][ni]);
      __builtin_amdgcn_s_setprio(0);
    }
    __builtin_amdgcn_sched_barrier(0);
    __builtin_amdgcn_s_barrier();     // all waves done reading buf (ds data already retired pre-MFMA)
    __builtin_amdgcn_sched_barrier(0);
    if (t + 2 < NT) STAGE_(buf, t + 2);
    VMCNT_L_();                       // tile t+1 landed; t+2's loads stay in flight (T4)
    __builtin_amdgcn_sched_barrier(0);
    __builtin_amdgcn_s_barrier();
    __builtin_amdgcn_sched_barrier(0);
  }
#undef STAGE_
#undef VMCNT_L_
  const int rl = khi * 4;
#pragma unroll
  for (int mi = 0; mi < MI; ++mi)
#pragma unroll
    for (int ni = 0; ni < NI; ++ni) {
      int col = n0 + wc * (BN / 4) + ni * 16 + cl;
#pragma unroll
      for (int r = 0; r < 4; ++r) {
        int rw = m0 + wr * (BM / 2) + mi * 16 + rl + r;
        if (OUT_F32) ((float*)Cp)[(size_t)rw * N + col] = acc[mi][ni][r];
        else         ((u16*)Cp)[(size_t)rw * N + col]   = f2bf(acc[mi][ni][r]);
      }
    }
}

// ---------------- RoPE + scatter (Q pre-scaled by SCALE*log2e for exp2-domain softmax) ----------------
__global__ __launch_bounds__(256) void k_rope(const u16* __restrict__ qkv, const float* __restrict__ cosT,
                                              const float* __restrict__ sinT, const int* __restrict__ sp,
                                              u16* __restrict__ qr, u16* __restrict__ kb,
                                              float* __restrict__ k_all, float* __restrict__ v_all) {
  int bt = blockIdx.x;
  int b = bt >> 9, t = bt & 511;
  int pos = sp[b] + t;
  const u16* row = qkv + (size_t)bt * NQKV;
  for (int idx = threadIdx.x; idx < 2560; idx += 256) {   // 40 roped heads * 64 pairs
    int head = idx >> 6, d = idx & 63;
    float c = cosT[pos * HD_ + d], s = sinT[pos * HD_ + d];
    float x1 = bf2f(row[head * HD_ + d]);
    float x2 = bf2f(row[head * HD_ + d + 64]);
    float y1 = x1 * c - x2 * s;
    float y2 = x2 * c + x1 * s;
    if (head < 32) {
      size_t o = (((size_t)b * H_ + head) * T_ + t) * HD_ + d;
      qr[o] = f2bf(y1 * QSC); qr[o + 64] = f2bf(y2 * QSC);
    } else {
      int g = head - 32;
      size_t o = (((size_t)b * G_ + g) * S_ + CACHE_ + t) * HD_ + d;
      kb[o] = f2bf(y1); kb[o + 64] = f2bf(y2);
      k_all[o] = y1; k_all[o + 64] = y2;
    }
  }
  for (int idx = threadIdx.x; idx < 1024; idx += 256) {   // v passthrough (f32 copy only)
    int g = idx >> 7;
    float v = bf2f(row[5120 + idx]);
    size_t o = (((size_t)b * G_ + g) * S_ + CACHE_ + t) * HD_ + (idx & 127);
    v_all[o] = v;
  }
}

// ---------------- transpose new-V slice into v_t[bg][hd][CACHE_..S] ----------------
__global__ __launch_bounds__(256) void k_tv_new(const u16* __restrict__ qkv, u16* __restrict__ vt) {
  __shared__ u16 tile[64][72];
  int bg = blockIdx.y;
  int b = bg >> 3, g = bg & 7;
  int tt = blockIdx.x >> 1, ht = blockIdx.x & 1;
  int t0 = tt * 64, hd0 = ht * 64;
  int t = threadIdx.x;
  int rr = t >> 3, c8 = (t & 7) * 8;
#pragma unroll
  for (int p = 0; p < 2; ++p) {
    int r = p * 32 + rr;
    *(u16x8*)(&tile[r][c8]) =
      *(const u16x8*)(qkv + (size_t)(b * T_ + t0 + r) * NQKV + 5120 + g * HD_ + hd0 + c8);
  }
  __syncthreads();
  int hr = t >> 4, s4 = (t & 15) * 4;
#pragma unroll
  for (int p = 0; p < 4; ++p) {
    int hd = p * 16 + hr;
    u16x4 o = { tile[s4][hd], tile[s4 + 1][hd], tile[s4 + 2][hd], tile[s4 + 3][hd] };
    *(u16x4*)(vt + ((size_t)bg * HD_ + hd0 + hd) * S_ + CACHE_ + t0 + s4) = o;
  }
}

// ---------------- flash attention v8: R7 proven structure (shfl_xor cross-lane) ----------------
// 8 waves x 32 q (256 q/block), grid 256 = 1 block/CU, XCD-grouped KV slabs, dbuf LDS
// single-barrier pipeline, max3 tree, 8-partial row-sum. Cross-lane via __shfl_xor —
// permlane32_swap reverted (R9/R10: on-HW pack semantics mismatch; probe before reuse).
__global__ __launch_bounds__(512) void k_attn(const u16* __restrict__ Q, const u16* __restrict__ Kc,
                                              const u16* __restrict__ Vt, const int* __restrict__ sp,
                                              u16* __restrict__ ctx) {
  __shared__ u16 Ks[2][64 * 128];   // [buf][kv64][16 chunks16B], chunk c at c ^ (row&15)
  __shared__ u16 Vs[2][128 * 64];   // [buf][hd128][8 chunks16B], chunk c at c ^ (row&7)
  const int xcd = blockIdx.x & 7, pos = blockIdx.x >> 3;
  const int wgid = xcd * 32 + pos;                 // nwg = 256; 8 consecutive share one (b,g)
  const int qh = wgid & 1, hq = (wgid >> 1) & 3, bg = wgid >> 3;
  const int b = bg >> 3, g = bg & 7, h = g * 4 + hq;
  const int tid = threadIdx.x, w = tid >> 6, lane = tid & 63;
  const int l31 = lane & 31, hh = lane >> 5;
  const int cache = sp[b];
  const int qbase = qh * 256;
  const int qtok = qbase + w * 32 + l31;           // this lane's softmax q-row
  const size_t kvoff = (size_t)bg * S_ * HD_;
  const u16* kp = Kc + kvoff;
  const u16* vp = Vt + kvoff;
  s16x8 qreg[8];
  {
    const u16* qb = Q + ((size_t)(b * H_ + h) * T_ + qtok) * HD_;
#pragma unroll
    for (int s = 0; s < 8; ++s) qreg[s] = *(const s16x8*)(qb + s * 16 + hh * 8);
  }
  f32x16 acc[4] = {};
  float mr = -1e30f, ls = 0.f;
  const int krow = w * 8 + (lane >> 3), kch = lane & 7;
  const int vrow = w * 16 + (lane >> 2), vch = lane & 3;
  const int kswz = (krow & 15) << 3;               // element offsets
  const int vswz = (vrow & 7) << 3;
  const int rdswzK = (l31 & 15) << 3;
  const int rdswzV = (l31 & 7) << 3;
  const int jm = (cache + qbase + w * 32) >> 6;    // first tile needing mask (per wave)
  const int jlastB = (cache + qbase + 255) >> 6;   // block-uniform loop bound
  const int kvlim = cache + qtok;
  u16x8 rk0, rk1, rv0, rv1;
  // prologue: tile 0 -> regs -> buf0; prefetch tile 1 -> regs
  rk0 = *(const u16x8*)(kp + (size_t)krow * HD_ + kch * 8);
  rk1 = *(const u16x8*)(kp + (size_t)krow * HD_ + (kch + 8) * 8);
  rv0 = *(const u16x8*)(vp + (size_t)vrow * S_ + vch * 8);
  rv1 = *(const u16x8*)(vp + (size_t)vrow * S_ + (vch + 4) * 8);
  *(u16x8*)(Ks[0] + krow * 128 + ((kch * 8) ^ kswz))       = rk0;
  *(u16x8*)(Ks[0] + krow * 128 + (((kch + 8) * 8) ^ kswz)) = rk1;
  *(u16x8*)(Vs[0] + vrow * 64 + ((vch * 8) ^ vswz))        = rv0;
  *(u16x8*)(Vs[0] + vrow * 64 + (((vch + 4) * 8) ^ vswz))  = rv1;
  rk0 = *(const u16x8*)(kp + (size_t)(64 + krow) * HD_ + kch * 8);
  rk1 = *(const u16x8*)(kp + (size_t)(64 + krow) * HD_ + (kch + 8) * 8);
  rv0 = *(const u16x8*)(vp + (size_t)vrow * S_ + 64 + vch * 8);
  rv1 = *(const u16x8*)(vp + (size_t)vrow * S_ + 64 + (vch + 4) * 8);
  __syncthreads();
  for (int j = 0; j <= jlastB; ++j) {
    const int buf = j & 1;
    const u16* KsB = Ks[buf];
    const u16* VsB = Vs[buf];
    u16* Ksn = Ks[buf ^ 1];
    u16* Vsn = Vs[buf ^ 1];
    // (1) QK issue: S^T[kv][q] = K-tile @ Q^T (2 kv-blocks of 32)
    f32x16 sa[2] = {};
    __builtin_amdgcn_s_setprio(1);
#pragma unroll
    for (int s = 0; s < 8; ++s) {
      s16x8 ka = *(const s16x8*)(KsB + l31 * 128 + ((s * 16 + hh * 8) ^ rdswzK));
      sa[0] = __builtin_amdgcn_mfma_f32_32x32x16_bf16(ka, qreg[s], sa[0], 0, 0, 0);
    }
#pragma unroll
    for (int s = 0; s < 8; ++s) {
      s16x8 ka = *(const s16x8*)(KsB + (32 + l31) * 128 + ((s * 16 + hh * 8) ^ rdswzK));
      sa[1] = __builtin_amdgcn_mfma_f32_32x32x16_bf16(ka, qreg[s], sa[1], 0, 0, 0);
    }
    __builtin_amdgcn_s_setprio(0);
    // (2) stage tile j+1 into buf^1 (its last readers finished before the previous barrier)
    if (j < jlastB) {
      *(u16x8*)(Ksn + krow * 128 + ((kch * 8) ^ kswz))       = rk0;
      *(u16x8*)(Ksn + krow * 128 + (((kch + 8) * 8) ^ kswz)) = rk1;
      *(u16x8*)(Vsn + vrow * 64 + ((vch * 8) ^ vswz))        = rv0;
      *(u16x8*)(Vsn + vrow * 64 + (((vch + 4) * 8) ^ vswz))  = rv1;
    }
    // (3) prefetch tile j+2 -> regs (in flight across softmax+PV)
    if (j + 2 <= jlastB) {
      rk0 = *(const u16x8*)(kp + (size_t)((j + 2) * 64 + krow) * HD_ + kch * 8);
      rk1 = *(const u16x8*)(kp + (size_t)((j + 2) * 64 + krow) * HD_ + (kch + 8) * 8);
      rv0 = *(const u16x8*)(vp + (size_t)vrow * S_ + (j + 2) * 64 + vch * 8);
      rv1 = *(const u16x8*)(vp + (size_t)vrow * S_ + (j + 2) * 64 + (vch + 4) * 8);
    }
    // (4) softmax
    if (j >= jm) {   // causal mask: only tiles >= jm can have masked kv
#pragma unroll
      for (int r = 0; r < 16; ++r) {
        int kv = j * 64 + (r & 3) + 8 * (r >> 2) + 4 * hh;
        if (kv > kvlim)      sa[0][r] = -1e30f;
        if (kv + 32 > kvlim) sa[1][r] = -1e30f;
      }
    }
    // row max: max3 tree (T17) + shfl lane^32 exchange (proven R7 form)
    float mx;
    {
      float t[16];
#pragma unroll
      for (int r = 0; r < 16; ++r) t[r] = fmaxf(sa[0][r], sa[1][r]);
#define F3_(a, b, c) fmaxf(fmaxf(a, b), c)
      float u0 = F3_(t[0], t[1], t[2]);
      float u1 = F3_(t[3], t[4], t[5]);
      float u2 = F3_(t[6], t[7], t[8]);
      float u3 = F3_(t[9], t[10], t[11]);
      float u4 = F3_(t[12], t[13], t[14]);
      float lm = fmaxf(F3_(u0, u1, u2), F3_(u3, u4, t[15]));
#undef F3_
      mx = fmaxf(lm, __shfl_xor(lm, 32));
    }
    // defer-max (T13): rescale only when max grew > 8 (exp2 domain)
    if (__any(mx > mr + 8.f)) {
      float nm = fmaxf(mr, mx);
      float al = __builtin_amdgcn_exp2f(mr - nm);
      mr = nm; ls *= al;
#pragma unroll
      for (int r = 0; r < 16; ++r) {
        float ar = __shfl(al, (r & 3) + 8 * (r >> 2) + 4 * hh, 64);
        acc[0][r] *= ar; acc[1][r] *= ar; acc[2][r] *= ar; acc[3][r] *= ar;
      }
    }
    // exp2 + row sum with 8 parallel partials (breaks the serial add chain)
    float p0 = 0.f, p1 = 0.f, p2 = 0.f, p3 = 0.f, p4 = 0.f, p5 = 0.f, p6 = 0.f, p7 = 0.f;
#pragma unroll
    for (int r = 0; r < 16; r += 4) {
      float e0 = __builtin_amdgcn_exp2f(sa[0][r]     - mr);
      float e1 = __builtin_amdgcn_exp2f(sa[0][r + 1] - mr);
      float e2 = __builtin_amdgcn_exp2f(sa[0][r + 2] - mr);
      float e3 = __builtin_amdgcn_exp2f(sa[0][r + 3] - mr);
      sa[0][r] = e0; sa[0][r + 1] = e1; sa[0][r + 2] = e2; sa[0][r + 3] = e3;
      p0 += e0; p1 += e1; p2 += e2; p3 += e3;
    }
#pragma unroll
    for (int r = 0; r < 16; r += 4) {
      float e0 = __builtin_amdgcn_exp2f(sa[1][r]     - mr);
      float e1 = __builtin_amdgcn_exp2f(sa[1][r + 1] - mr);
      float e2 = __builtin_amdgcn_exp2f(sa[1][r + 2] - mr);
      float e3 = __builtin_amdgcn_exp2f(sa[1][r + 3] - mr);
      sa[1][r] = e0; sa[1][r + 1] = e1; sa[1][r + 2] = e2; sa[1][r + 3] = e3;
      p4 += e0; p5 += e1; p6 += e2; p7 += e3;
    }
    float rsum = ((p0 + p1) + (p2 + p3)) + ((p4 + p5) + (p6 + p7));
    ls += rsum + __shfl_xor(rsum, 32);
    // pack P (D-layout) into 4 MFMA A-frags (proven R7 form: shfl_xor + select)
    s16x8 pf[4];
#pragma unroll
    for (int sb = 0; sb < 2; ++sb) {
      u32 a0 = pkbf(sa[sb][0],  sa[sb][1]),  a1 = pkbf(sa[sb][2],  sa[sb][3]);
      u32 b0 = pkbf(sa[sb][4],  sa[sb][5]),  b1 = pkbf(sa[sb][6],  sa[sb][7]);
      u32 c0 = pkbf(sa[sb][8],  sa[sb][9]),  c1 = pkbf(sa[sb][10], sa[sb][11]);
      u32 d0 = pkbf(sa[sb][12], sa[sb][13]), d1 = pkbf(sa[sb][14], sa[sb][15]);
      u32 xa0 = __shfl_xor(a0, 32), xa1 = __shfl_xor(a1, 32);
      u32 xb0 = __shfl_xor(b0, 32), xb1 = __shfl_xor(b1, 32);
      u32 xc0 = __shfl_xor(c0, 32), xc1 = __shfl_xor(c1, 32);
      u32 xd0 = __shfl_xor(d0, 32), xd1 = __shfl_xor(d1, 32);
      u32x4 f0 = { hh ? xb0 : a0, hh ? xb1 : a1, hh ? b0 : xa0, hh ? b1 : xa1 };
      u32x4 f1 = { hh ? xd0 : c0, hh ? xd1 : c1, hh ? d0 : xc0, hh ? d1 : xc1 };
      pf[sb * 2]     = __builtin_bit_cast(s16x8, f0);
      pf[sb * 2 + 1] = __builtin_bit_cast(s16x8, f1);
    }
    // (5) O += P V  (B-frags straight from swizzled Vs)
    __builtin_amdgcn_s_setprio(1);
#pragma unroll
    for (int hb = 0; hb < 4; ++hb) {
      const int vro = hb * 32 + l31;
#pragma unroll
      for (int kb = 0; kb < 4; ++kb) {
        s16x8 vb = *(const s16x8*)(VsB + vro * 64 + ((kb * 16 + hh * 8) ^ rdswzV));
        acc[hb] = __builtin_amdgcn_mfma_f32_32x32x16_bf16(pf[kb], vb, acc[hb], 0, 0, 0);
      }
    }
    __builtin_amdgcn_s_setprio(0);
    // (6) single barrier: publishes buf^1 (tile j+1), retires all reads of buf (tile j)
    __syncthreads();
  }
  // epilogue: normalize rows (ls lives at lane l31==row) and store ctx
  float inv = 1.0f / ls;
#pragma unroll
  for (int r = 0; r < 16; ++r) {
    int ql = (r & 3) + 8 * (r >> 2) + 4 * hh;
    float ivr = __shfl(inv, ql, 64);
    u16* cb = ctx + ((size_t)(b * T_ + qbase + w * 32 + ql)) * 4096 + h * HD_ + l31;
    cb[0]  = f2bf(acc[0][r] * ivr);
    cb[32] = f2bf(acc[1][r] * ivr);
    cb[64] = f2bf(acc[2][r] * ivr);
    cb[96] = f2bf(acc[3][r] * ivr);
  }
}

// ---------------- launch ----------------
extern "C" void kernel_launch(void* const* d_in, const int* in_sizes, int n_in,
                              void* d_out, int out_size, void* d_ws, size_t ws_size,
                              hipStream_t stream) {
  const float* x      = (const float*)d_in[0];
  // d_in[1] = mask (derived analytically; unused)
  const float* cosT   = (const float*)d_in[2];
  const float* sinT   = (const float*)d_in[3];
  const int*   sp     = (const int*)d_in[4];
  const float* prev_k = (const float*)d_in[5];
  const float* prev_v = (const float*)d_in[6];
  const float* q_w    = (const float*)d_in[7];
  const float* k_w    = (const float*)d_in[8];
  const float* v_w    = (const float*)d_in[9];
  const float* o_w    = (const float*)d_in[10];

  float* out   = (float*)d_out;
  float* k_all = out + (size_t)B_ * T_ * H_ * HD_;      // +8388608
  float* v_all = k_all + (size_t)B_ * G_ * S_ * HD_;    // +16777216

  char* w = (char*)d_ws;
  u16* wt_qkv = (u16*)(w);                 // [6144][4096] bf16   50331648 B
  u16* wt_o   = (u16*)(w + 50331648);      // [4096][4096] bf16   33554432 B
  u16* x_bf   = (u16*)(w + 83886080);      // [2048][4096] bf16   16777216 B
  u16* qkv_bf = (u16*)(w + 100663296);     // [2048][6144] bf16   25165824 B
  u16* q_rope = (u16*)(w + 125829120);     // [4][32][512][128]   16777216 B
  u16* k_bf   = (u16*)(w + 142606336);     // [4][8][4096][128]   33554432 B
  u16* v_t    = (u16*)(w + 176160768);     // [4][8][128][4096]   33554432 B
  u16* ctx    = (u16*)(w + 209715200);     // [2048][4096]        16777216 B
  if (ws_size < 226492416ull) return;      // workspace too small -> bench will flag it

  k_prep_w<<<dim3(64, 288), 256, 0, stream>>>(q_w, k_w, v_w, o_w, x, wt_qkv, wt_o, x_bf);
  k_prep_kv<<<dim3(504, 32), 256, 0, stream>>>(prev_k, prev_v, k_all, v_all, k_bf, v_t);
  k_gemm2<256, 192, false><<<256, 512, 0, stream>>>(x_bf, wt_qkv, qkv_bf, M_, NQKV, 4096);
  k_rope<<<2048, 256, 0, stream>>>(qkv_bf, cosT, sinT, sp, q_rope, k_bf, k_all, v_all);
  k_tv_new<<<dim3(16, 32), 256, 0, stream>>>(qkv_bf, v_t);
  k_attn<<<256, 512, 0, stream>>>(q_rope, k_bf, v_t, sp, ctx);
  k_gemm2<128, 256, true><<<256, 512, 0, stream>>>(ctx, wt_o, out, M_, 4096, 4096);
}

// Round 13
// 505.080 us; speedup vs baseline: 1.0889x; 1.0061x over previous
//
#include <hip/hip_runtime.h>

// ---------------- problem constants ----------------
#define B_     4
#define T_     512
#define DIN    4096
#define H_     32
#define G_     8
#define HD_    128
#define S_     4096
#define CACHE_ 3584
#define M_     2048          // B*T
#define NQKV   6144          // H*HD + 2*G*HD
#define SCALE  0.08838834764831843f  // 1/sqrt(128)
#define LOG2E  1.4426950408889634f
#define QSC    (SCALE * LOG2E)       // folded into Q at rope time -> softmax in exp2 domain

typedef __attribute__((ext_vector_type(4)))  float  f32x4;
typedef __attribute__((ext_vector_type(16))) float  f32x16;
typedef __attribute__((ext_vector_type(8)))  short  s16x8;   // 8 bf16 (4 VGPRs) MFMA frag
typedef __attribute__((ext_vector_type(4)))  unsigned short u16x4;
typedef __attribute__((ext_vector_type(8)))  unsigned short u16x8;
typedef __attribute__((ext_vector_type(4)))  unsigned int   u32x4;
typedef unsigned short u16;
typedef unsigned int   u32;

__device__ __forceinline__ u16 f2bf(float f) {
  u32 u = __builtin_bit_cast(u32, f);
  return (u16)((u + 0x7fffu + ((u >> 16) & 1u)) >> 16);   // RNE
}
__device__ __forceinline__ float bf2f(u16 h) {
  return __builtin_bit_cast(float, (u32)h << 16);
}
__device__ __forceinline__ f32x4 mfma16(s16x8 a, s16x8 b, f32x4 c) {
  return __builtin_amdgcn_mfma_f32_16x16x32_bf16(a, b, c, 0, 0, 0);
}
__device__ __forceinline__ u32 pkbf(float a, float b) {   // pack 2 f32 -> 2 bf16 (RNE)
  u32 r; asm("v_cvt_pk_bf16_f32 %0, %1, %2" : "=v"(r) : "v"(a), "v"(b)); return r;
}
// async global->LDS, 16B per lane; LDS dest is wave-uniform base + lane*16
__device__ __forceinline__ void gload_lds16(const void* g, void* l) {
  __builtin_amdgcn_global_load_lds((__attribute__((address_space(1))) void*)g,
                                   (__attribute__((address_space(3))) void*)l, 16, 0, 0);
}

// ---------------- merged prep: x f32->bf16 + 4 weight transposes ----------------
// grid (64, 288): by<64 q_w | by<80 k_w | by<96 v_w | by<160 o_w | by>=160 cvt_x
__global__ __launch_bounds__(256) void k_prep_w(const float* __restrict__ qw, const float* __restrict__ kw,
                                                const float* __restrict__ vw, const float* __restrict__ ow,
                                                const float* __restrict__ x,
                                                u16* __restrict__ wt_qkv, u16* __restrict__ wt_o,
                                                u16* __restrict__ xb) {
  const int bx = blockIdx.x, by = blockIdx.y, t = threadIdx.x;
  if (by >= 160) {   // cvt_x: 8192 linear blocks
    size_t i = (((size_t)(by - 160) * 64 + bx) * 256 + t) * 4;
    f32x4 v = *(const f32x4*)(x + i);
    u16x4 o = { f2bf(v[0]), f2bf(v[1]), f2bf(v[2]), f2bf(v[3]) };
    *(u16x4*)(xb + i) = o;
    return;
  }
  __shared__ float tile[64][68];
  const float* src; u16* dst; int ldn, n0;
  if (by < 64)      { src = qw; ldn = 4096; dst = wt_qkv;                         n0 = by * 64; }
  else if (by < 80) { src = kw; ldn = 1024; dst = wt_qkv + (size_t)4096 * 4096;   n0 = (by - 64) * 64; }
  else if (by < 96) { src = vw; ldn = 1024; dst = wt_qkv + (size_t)5120 * 4096;   n0 = (by - 80) * 64; }
  else              { src = ow; ldn = 4096; dst = wt_o;                           n0 = (by - 96) * 64; }
  const int k0 = bx * 64;
  int rr = t >> 4, cc = (t & 15) * 4;
#pragma unroll
  for (int p = 0; p < 4; ++p) {
    int r = p * 16 + rr;
    f32x4 v = *(const f32x4*)(src + (size_t)(k0 + r) * ldn + n0 + cc);
    tile[r][cc] = v[0]; tile[r][cc + 1] = v[1]; tile[r][cc + 2] = v[2]; tile[r][cc + 3] = v[3];
  }
  __syncthreads();
#pragma unroll
  for (int p = 0; p < 4; ++p) {
    int n = p * 16 + rr;
    u16x4 o = { f2bf(tile[cc][n]), f2bf(tile[cc + 1][n]), f2bf(tile[cc + 2][n]), f2bf(tile[cc + 3][n]) };
    *(u16x4*)(dst + (size_t)(n0 + n) * 4096 + k0 + cc) = o;
  }
}

// ---------------- merged prep: prev_k copy+bf16 / prev_v copy+transposed bf16 ----------------
// grid (504, 32): bx<448 -> prep_k; bx>=448 -> prep_v (s0=(bx-448)*64)
__global__ __launch_bounds__(256) void k_prep_kv(const float* __restrict__ pk, const float* __restrict__ pv,
                                                 float* __restrict__ k_all, float* __restrict__ v_all,
                                                 u16* __restrict__ kb, u16* __restrict__ vt) {
  __shared__ float tile[64][132];
  const int bg = blockIdx.y, t = threadIdx.x;
  if (blockIdx.x < 448) {
    size_t si = ((size_t)blockIdx.x * 256 + t) * 4;   // < 3584*128
    f32x4 v = *(const f32x4*)(pk + (size_t)bg * CACHE_ * HD_ + si);
    size_t dof = (size_t)bg * S_ * HD_ + si;
    *(f32x4*)(k_all + dof) = v;
    u16x4 o = { f2bf(v[0]), f2bf(v[1]), f2bf(v[2]), f2bf(v[3]) };
    *(u16x4*)(kb + dof) = o;
    return;
  }
  const int s0 = (blockIdx.x - 448) * 64;
  const float* src = pv + ((size_t)bg * CACHE_ + s0) * HD_;
  float* dc = v_all + ((size_t)bg * S_ + s0) * HD_;
  int r8 = t >> 5, c4 = (t & 31) * 4;
#pragma unroll
  for (int p = 0; p < 8; ++p) {
    int r = p * 8 + r8;
    f32x4 v = *(const f32x4*)(src + (size_t)r * HD_ + c4);
    *(f32x4*)(dc + (size_t)r * HD_ + c4) = v;
    tile[r][c4] = v[0]; tile[r][c4 + 1] = v[1]; tile[r][c4 + 2] = v[2]; tile[r][c4 + 3] = v[3];
  }
  __syncthreads();
  int hr = t >> 4, s4 = (t & 15) * 4;
#pragma unroll
  for (int p = 0; p < 8; ++p) {
    int hd = p * 16 + hr;
    u16x4 o = { f2bf(tile[s4][hd]), f2bf(tile[s4 + 1][hd]), f2bf(tile[s4 + 2][hd]), f2bf(tile[s4 + 3][hd]) };
    *(u16x4*)(vt + ((size_t)bg * HD_ + hd) * S_ + s0 + s4) = o;
  }
}

// ---------------- GEMM v3: C[M][N] = A[M][K]bf16 @ Bt[N][K]bf16 ----------------
template<int BM, int BN, bool OUT_F32>
__global__ __launch_bounds__(512, 1) void k_gemm2(const u16* __restrict__ A, const u16* __restrict__ Bt,
                                                  void* __restrict__ Cp, int M, int N, int K) {
  constexpr int MI = BM / 32;        // A-frag repeats per wave (8 or 4)
  constexpr int NI = BN / 64;        // B-frag repeats per wave (3 or 4); per-wave N = BN/4
  constexpr int LA = BM / 64;        // A stage loads/thread per K-tile (4 or 2)
  constexpr int VM = LA + NI;        // counted vmcnt: one full tile's loads in flight
  __shared__ u16 As[2 * BM * 64];    // [buf][BM][64], chunk16 ch' = ch ^ (row&7)
  __shared__ u16 Bs[2 * BN * 64];
  const int tid = threadIdx.x, w = tid >> 6, lane = tid & 63;
  const int wr = w >> 2, wc = w & 3;             // wave tile: rows wr*(BM/2), cols wc*(BN/4)
  const int cl = lane & 15, khi = lane >> 4;
  // --- T1: bijective XCD swizzle, column-major (bm fast) ---
  const int Mt = M / BM;
  const int nwg = gridDim.x;
  const int q = nwg >> 3, r8 = nwg & 7;
  const int xcd = blockIdx.x & 7, pos = blockIdx.x >> 3;
  const int wgid = (xcd < r8 ? xcd * (q + 1) : r8 * (q + 1) + (xcd - r8) * q) + pos;
  const int m0 = (wgid % Mt) * BM, n0 = (wgid / Mt) * BN;
  // --- staging addresses (inverse-swizzled global source) ---
  const int rb = tid >> 3;                       // 0..63
  const int csw = ((tid & 7) ^ (rb & 7)) * 8;    // element offset, pre-swizzled
  const u16* aS = A  + (size_t)(m0 + rb) * K + csw;
  const u16* bS = Bt + (size_t)(n0 + rb) * K + csw;
  u16* aD = As + w * 512;                        // + buf*BM*64 + i*4096; lane*16B implicit
  u16* bD = Bs + w * 512;
  // --- swizzled read chunk offsets (row&7 == cl&7 for all frags; BN/4 % 8 == 0) ---
  const int ck0 = ((0 + khi) ^ (cl & 7)) * 8;
  const int ck1 = ((4 + khi) ^ (cl & 7)) * 8;
  const int NT = K >> 6;
  f32x4 acc[MI][NI] = {};

#define STAGE_(buf, tt)                                                                   \
  do {                                                                                    \
    _Pragma("unroll")                                                                     \
    for (int i = 0; i < LA; ++i)                                                          \
      gload_lds16(aS + (size_t)(i * 64) * K + (size_t)(tt) * 64, aD + (buf) * (BM * 64) + i * 4096); \
    _Pragma("unroll")                                                                     \
    for (int i = 0; i < NI; ++i)                                                          \
      gload_lds16(bS + (size_t)(i * 64) * K + (size_t)(tt) * 64, bD + (buf) * (BN * 64) + i * 4096); \
  } while (0)
#define VMCNT_L_()                                                                        \
  do {                                                                                    \
    if constexpr (VM == 8)      asm volatile("s_waitcnt vmcnt(8)" ::: "memory");          \
    else if constexpr (VM == 7) asm volatile("s_waitcnt vmcnt(7)" ::: "memory");          \
    else                        asm volatile("s_waitcnt vmcnt(6)" ::: "memory");          \
  } while (0)

  STAGE_(0, 0);
  STAGE_(1, 1);
  VMCNT_L_();
  __builtin_amdgcn_sched_barrier(0);
  __builtin_amdgcn_s_barrier();
  __builtin_amdgcn_sched_barrier(0);

  for (int t = 0; t < NT; ++t) {
    const int buf = t & 1;
    const int ab = buf * (BM * 64) + (wr * (BM / 2) + cl) * 64;
    const int bb = buf * (BN * 64) + (wc * (BN / 4) + cl) * 64;
#pragma unroll
    for (int kk = 0; kk < 2; ++kk) {
      const int ck = kk ? ck1 : ck0;
      s16x8 bf4[NI], af[MI];
#pragma unroll
      for (int ni = 0; ni < NI; ++ni) bf4[ni] = *(const s16x8*)(Bs + bb + ni * 16 * 64 + ck);
#pragma unroll
      for (int mi = 0; mi < MI; ++mi) af[mi] = *(const s16x8*)(As + ab + mi * 16 * 64 + ck);
      __builtin_amdgcn_s_setprio(1);
#pragma unroll
      for (int mi = 0; mi < MI; ++mi)
#pragma unroll
        for (int ni = 0; ni < NI; ++ni)
          acc[mi][ni] = mfma16(af[mi], bf4[ni], acc[mi][ni]);
      __builtin_amdgcn_s_setprio(0);
    }
    __builtin_amdgcn_sched_barrier(0);
    __builtin_amdgcn_s_barrier();     // all waves done reading buf (ds data already retired pre-MFMA)
    __builtin_amdgcn_sched_barrier(0);
    if (t + 2 < NT) STAGE_(buf, t + 2);
    VMCNT_L_();                       // tile t+1 landed; t+2's loads stay in flight (T4)
    __builtin_amdgcn_sched_barrier(0);
    __builtin_amdgcn_s_barrier();
    __builtin_amdgcn_sched_barrier(0);
  }
#undef STAGE_
#undef VMCNT_L_
  const int rl = khi * 4;
#pragma unroll
  for (int mi = 0; mi < MI; ++mi)
#pragma unroll
    for (int ni = 0; ni < NI; ++ni) {
      int col = n0 + wc * (BN / 4) + ni * 16 + cl;
#pragma unroll
      for (int r = 0; r < 4; ++r) {
        int rw = m0 + wr * (BM / 2) + mi * 16 + rl + r;
        if (OUT_F32) ((float*)Cp)[(size_t)rw * N + col] = acc[mi][ni][r];
        else         ((u16*)Cp)[(size_t)rw * N + col]   = f2bf(acc[mi][ni][r]);
      }
    }
}

// ---------------- RoPE + scatter, vectorized (u16x4/f32x4) ----------------
__global__ __launch_bounds__(256) void k_rope(const u16* __restrict__ qkv, const float* __restrict__ cosT,
                                              const float* __restrict__ sinT, const int* __restrict__ sp,
                                              u16* __restrict__ qr, u16* __restrict__ kb,
                                              float* __restrict__ k_all, float* __restrict__ v_all) {
  int bt = blockIdx.x;
  int b = bt >> 9, t = bt & 511;
  int pos = sp[b] + t;
  const u16* row = qkv + (size_t)bt * NQKV;
  const float* cp = cosT + (size_t)pos * HD_;
  const float* sq = sinT + (size_t)pos * HD_;
  for (int hp = threadIdx.x; hp < 640; hp += 256) {   // 40 roped heads * 16 quads
    int head = hp >> 4, q4 = (hp & 15) * 4;           // q4 in [0,64)
    f32x4 c = *(const f32x4*)(cp + q4);
    f32x4 s = *(const f32x4*)(sq + q4);
    u16x4 xa = *(const u16x4*)(row + head * HD_ + q4);
    u16x4 xb = *(const u16x4*)(row + head * HD_ + q4 + 64);
    f32x4 y1, y2;
#pragma unroll
    for (int e = 0; e < 4; ++e) {
      float x1 = bf2f(xa[e]), x2 = bf2f(xb[e]);
      y1[e] = x1 * c[e] - x2 * s[e];
      y2[e] = x2 * c[e] + x1 * s[e];
    }
    if (head < 32) {
      size_t o = (((size_t)b * H_ + head) * T_ + t) * HD_ + q4;
      u16x4 o1 = { f2bf(y1[0] * QSC), f2bf(y1[1] * QSC), f2bf(y1[2] * QSC), f2bf(y1[3] * QSC) };
      u16x4 o2 = { f2bf(y2[0] * QSC), f2bf(y2[1] * QSC), f2bf(y2[2] * QSC), f2bf(y2[3] * QSC) };
      *(u16x4*)(qr + o) = o1;
      *(u16x4*)(qr + o + 64) = o2;
    } else {
      int g = head - 32;
      size_t o = (((size_t)b * G_ + g) * S_ + CACHE_ + t) * HD_ + q4;
      u16x4 o1 = { f2bf(y1[0]), f2bf(y1[1]), f2bf(y1[2]), f2bf(y1[3]) };
      u16x4 o2 = { f2bf(y2[0]), f2bf(y2[1]), f2bf(y2[2]), f2bf(y2[3]) };
      *(u16x4*)(kb + o) = o1;
      *(u16x4*)(kb + o + 64) = o2;
      *(f32x4*)(k_all + o) = y1;
      *(f32x4*)(k_all + o + 64) = y2;
    }
  }
  {   // v passthrough: 1024 f32 = 256 quads, one per thread
    int vq = threadIdx.x;
    int g = vq >> 5, d4 = (vq & 31) * 4;
    u16x4 v = *(const u16x4*)(row + 5120 + g * HD_ + d4);
    f32x4 vf = { bf2f(v[0]), bf2f(v[1]), bf2f(v[2]), bf2f(v[3]) };
    *(f32x4*)(v_all + (((size_t)b * G_ + g) * S_ + CACHE_ + t) * HD_ + d4) = vf;
  }
}

// ---------------- transpose new-V slice into v_t[bg][hd][CACHE_..S] ----------------
__global__ __launch_bounds__(256) void k_tv_new(const u16* __restrict__ qkv, u16* __restrict__ vt) {
  __shared__ u16 tile[64][72];
  int bg = blockIdx.y;
  int b = bg >> 3, g = bg & 7;
  int tt = blockIdx.x >> 1, ht = blockIdx.x & 1;
  int t0 = tt * 64, hd0 = ht * 64;
  int t = threadIdx.x;
  int rr = t >> 3, c8 = (t & 7) * 8;
#pragma unroll
  for (int p = 0; p < 2; ++p) {
    int r = p * 32 + rr;
    *(u16x8*)(&tile[r][c8]) =
      *(const u16x8*)(qkv + (size_t)(b * T_ + t0 + r) * NQKV + 5120 + g * HD_ + hd0 + c8);
  }
  __syncthreads();
  int hr = t >> 4, s4 = (t & 15) * 4;
#pragma unroll
  for (int p = 0; p < 4; ++p) {
    int hd = p * 16 + hr;
    u16x4 o = { tile[s4][hd], tile[s4 + 1][hd], tile[s4 + 2][hd], tile[s4 + 3][hd] };
    *(u16x4*)(vt + ((size_t)bg * HD_ + hd0 + hd) * S_ + CACHE_ + t0 + s4) = o;
  }
}

// ---------------- flash attention v9: R11 structure + intra-tile sub-tile pipeline ----------------
// Per 64-kv tile: QK(sa0)+QK(sa1) issued back-to-back, then {softmax0 -> PV kb01} with
// softmax1 overlapping PV kb01's MFMAs, then PV kb23. Two independent online-softmax
// updates per tile (32-kv granularity). No sync/layout changes vs R11.
__global__ __launch_bounds__(512) void k_attn(const u16* __restrict__ Q, const u16* __restrict__ Kc,
                                              const u16* __restrict__ Vt, const int* __restrict__ sp,
                                              u16* __restrict__ ctx) {
  __shared__ u16 Ks[2][64 * 128];   // [buf][kv64][16 chunks16B], chunk c at c ^ (row&15)
  __shared__ u16 Vs[2][128 * 64];   // [buf][hd128][8 chunks16B], chunk c at c ^ (row&7)
  const int xcd = blockIdx.x & 7, pos = blockIdx.x >> 3;
  const int wgid = xcd * 32 + pos;                 // nwg = 256; 8 consecutive share one (b,g)
  const int qh = wgid & 1, hq = (wgid >> 1) & 3, bg = wgid >> 3;
  const int b = bg >> 3, g = bg & 7, h = g * 4 + hq;
  const int tid = threadIdx.x, w = tid >> 6, lane = tid & 63;
  const int l31 = lane & 31, hh = lane >> 5;
  const int cache = sp[b];
  const int qbase = qh * 256;
  const int qtok = qbase + w * 32 + l31;           // this lane's softmax q-row
  const size_t kvoff = (size_t)bg * S_ * HD_;
  const u16* kp = Kc + kvoff;
  const u16* vp = Vt + kvoff;
  s16x8 qreg[8];
  {
    const u16* qb = Q + ((size_t)(b * H_ + h) * T_ + qtok) * HD_;
#pragma unroll
    for (int s = 0; s < 8; ++s) qreg[s] = *(const s16x8*)(qb + s * 16 + hh * 8);
  }
  f32x16 acc[4] = {};
  float mr = -1e30f, ls = 0.f;
  const int krow = w * 8 + (lane >> 3), kch = lane & 7;
  const int vrow = w * 16 + (lane >> 2), vch = lane & 3;
  const int kswz = (krow & 15) << 3;               // element offsets
  const int vswz = (vrow & 7) << 3;
  const int rdswzK = (l31 & 15) << 3;
  const int rdswzV = (l31 & 7) << 3;
  const int jm = (cache + qbase + w * 32) >> 6;    // first tile needing mask (per wave)
  const int jlastB = (cache + qbase + 255) >> 6;   // block-uniform loop bound
  const int kvlim = cache + qtok;
  u16x8 rk0, rk1, rv0, rv1;
  // prologue: tile 0 -> regs -> buf0; prefetch tile 1 -> regs
  rk0 = *(const u16x8*)(kp + (size_t)krow * HD_ + kch * 8);
  rk1 = *(const u16x8*)(kp + (size_t)krow * HD_ + (kch + 8) * 8);
  rv0 = *(const u16x8*)(vp + (size_t)vrow * S_ + vch * 8);
  rv1 = *(const u16x8*)(vp + (size_t)vrow * S_ + (vch + 4) * 8);
  *(u16x8*)(Ks[0] + krow * 128 + ((kch * 8) ^ kswz))       = rk0;
  *(u16x8*)(Ks[0] + krow * 128 + (((kch + 8) * 8) ^ kswz)) = rk1;
  *(u16x8*)(Vs[0] + vrow * 64 + ((vch * 8) ^ vswz))        = rv0;
  *(u16x8*)(Vs[0] + vrow * 64 + (((vch + 4) * 8) ^ vswz))  = rv1;
  rk0 = *(const u16x8*)(kp + (size_t)(64 + krow) * HD_ + kch * 8);
  rk1 = *(const u16x8*)(kp + (size_t)(64 + krow) * HD_ + (kch + 8) * 8);
  rv0 = *(const u16x8*)(vp + (size_t)vrow * S_ + 64 + vch * 8);
  rv1 = *(const u16x8*)(vp + (size_t)vrow * S_ + 64 + (vch + 4) * 8);
  __syncthreads();
  for (int j = 0; j <= jlastB; ++j) {
    const int buf = j & 1;
    const u16* KsB = Ks[buf];
    const u16* VsB = Vs[buf];
    u16* Ksn = Ks[buf ^ 1];
    u16* Vsn = Vs[buf ^ 1];
    // (1) QK issue for BOTH kv-halves back-to-back
    f32x16 sa[2] = {};
    __builtin_amdgcn_s_setprio(1);
#pragma unroll
    for (int s = 0; s < 8; ++s) {
      s16x8 ka = *(const s16x8*)(KsB + l31 * 128 + ((s * 16 + hh * 8) ^ rdswzK));
      sa[0] = __builtin_amdgcn_mfma_f32_32x32x16_bf16(ka, qreg[s], sa[0], 0, 0, 0);
    }
#pragma unroll
    for (int s = 0; s < 8; ++s) {
      s16x8 ka = *(const s16x8*)(KsB + (32 + l31) * 128 + ((s * 16 + hh * 8) ^ rdswzK));
      sa[1] = __builtin_amdgcn_mfma_f32_32x32x16_bf16(ka, qreg[s], sa[1], 0, 0, 0);
    }
    __builtin_amdgcn_s_setprio(0);
    // (2) stage tile j+1 into buf^1 (its last readers finished before the previous barrier)
    if (j < jlastB) {
      *(u16x8*)(Ksn + krow * 128 + ((kch * 8) ^ kswz))       = rk0;
      *(u16x8*)(Ksn + krow * 128 + (((kch + 8) * 8) ^ kswz)) = rk1;
      *(u16x8*)(Vsn + vrow * 64 + ((vch * 8) ^ vswz))        = rv0;
      *(u16x8*)(Vsn + vrow * 64 + (((vch + 4) * 8) ^ vswz))  = rv1;
    }
    // (3) prefetch tile j+2 -> regs (in flight across softmax+PV)
    if (j + 2 <= jlastB) {
      rk0 = *(const u16x8*)(kp + (size_t)((j + 2) * 64 + krow) * HD_ + kch * 8);
      rk1 = *(const u16x8*)(kp + (size_t)((j + 2) * 64 + krow) * HD_ + (kch + 8) * 8);
      rv0 = *(const u16x8*)(vp + (size_t)vrow * S_ + (j + 2) * 64 + vch * 8);
      rv1 = *(const u16x8*)(vp + (size_t)vrow * S_ + (j + 2) * 64 + (vch + 4) * 8);
    }
    // (4)+(5) two 32-kv sub-tiles: softmax(sb) then PV(sb); softmax of sb=1 overlaps PV of sb=0
#pragma unroll
    for (int sb = 0; sb < 2; ++sb) {
      // causal mask for this half
      if (j >= jm) {
#pragma unroll
        for (int r = 0; r < 16; ++r) {
          int kv = j * 64 + sb * 32 + (r & 3) + 8 * (r >> 2) + 4 * hh;
          if (kv > kvlim) sa[sb][r] = -1e30f;
        }
      }
      // half row-max: max3 tree + lane^32 exchange
      float mx;
      {
        float* t = (float*)&sa[sb];
#define F3_(a, b, c) fmaxf(fmaxf(a, b), c)
        float u0 = F3_(t[0], t[1], t[2]);
        float u1 = F3_(t[3], t[4], t[5]);
        float u2 = F3_(t[6], t[7], t[8]);
        float u3 = F3_(t[9], t[10], t[11]);
        float u4 = F3_(t[12], t[13], t[14]);
        float lm = fmaxf(F3_(u0, u1, u2), F3_(u3, u4, t[15]));
#undef F3_
        mx = fmaxf(lm, __shfl_xor(lm, 32));
      }
      // defer-max (T13)
      if (__any(mx > mr + 8.f)) {
        float nm = fmaxf(mr, mx);
        float al = __builtin_amdgcn_exp2f(mr - nm);
        mr = nm; ls *= al;
#pragma unroll
        for (int r = 0; r < 16; ++r) {
          float ar = __shfl(al, (r & 3) + 8 * (r >> 2) + 4 * hh, 64);
          acc[0][r] *= ar; acc[1][r] *= ar; acc[2][r] *= ar; acc[3][r] *= ar;
        }
      }
      // exp2 + half row-sum with 4 parallel partials
      float p0 = 0.f, p1 = 0.f, p2 = 0.f, p3 = 0.f;
#pragma unroll
      for (int r = 0; r < 16; r += 4) {
        float e0 = __builtin_amdgcn_exp2f(sa[sb][r]     - mr);
        float e1 = __builtin_amdgcn_exp2f(sa[sb][r + 1] - mr);
        float e2 = __builtin_amdgcn_exp2f(sa[sb][r + 2] - mr);
        float e3 = __builtin_amdgcn_exp2f(sa[sb][r + 3] - mr);
        sa[sb][r] = e0; sa[sb][r + 1] = e1; sa[sb][r + 2] = e2; sa[sb][r + 3] = e3;
        p0 += e0; p1 += e1; p2 += e2; p3 += e3;
      }
      float rsum = (p0 + p1) + (p2 + p3);
      ls += rsum + __shfl_xor(rsum, 32);
      // pack this half into 2 MFMA A-frags (proven shfl_xor + select form)
      s16x8 pf0, pf1;
      {
        u32 a0 = pkbf(sa[sb][0],  sa[sb][1]),  a1 = pkbf(sa[sb][2],  sa[sb][3]);
        u32 b0 = pkbf(sa[sb][4],  sa[sb][5]),  b1 = pkbf(sa[sb][6],  sa[sb][7]);
        u32 c0 = pkbf(sa[sb][8],  sa[sb][9]),  c1 = pkbf(sa[sb][10], sa[sb][11]);
        u32 d0 = pkbf(sa[sb][12], sa[sb][13]), d1 = pkbf(sa[sb][14], sa[sb][15]);
        u32 xa0 = __shfl_xor(a0, 32), xa1 = __shfl_xor(a1, 32);
        u32 xb0 = __shfl_xor(b0, 32), xb1 = __shfl_xor(b1, 32);
        u32 xc0 = __shfl_xor(c0, 32), xc1 = __shfl_xor(c1, 32);
        u32 xd0 = __shfl_xor(d0, 32), xd1 = __shfl_xor(d1, 32);
        u32x4 f0 = { hh ? xb0 : a0, hh ? xb1 : a1, hh ? b0 : xa0, hh ? b1 : xa1 };
        u32x4 f1 = { hh ? xd0 : c0, hh ? xd1 : c1, hh ? d0 : xc0, hh ? d1 : xc1 };
        pf0 = __builtin_bit_cast(s16x8, f0);
        pf1 = __builtin_bit_cast(s16x8, f1);
      }
      // PV for this half (kb = 2*sb, 2*sb+1); next half's softmax overlaps these MFMAs
      __builtin_amdgcn_s_setprio(1);
#pragma unroll
      for (int hb = 0; hb < 4; ++hb) {
        const int vro = hb * 32 + l31;
        s16x8 vb0 = *(const s16x8*)(VsB + vro * 64 + (((sb * 2) * 16 + hh * 8) ^ rdswzV));
        s16x8 vb1 = *(const s16x8*)(VsB + vro * 64 + (((sb * 2 + 1) * 16 + hh * 8) ^ rdswzV));
        acc[hb] = __builtin_amdgcn_mfma_f32_32x32x16_bf16(pf0, vb0, acc[hb], 0, 0, 0);
        acc[hb] = __builtin_amdgcn_mfma_f32_32x32x16_bf16(pf1, vb1, acc[hb], 0, 0, 0);
      }
      __builtin_amdgcn_s_setprio(0);
    }
    // (6) single barrier: publishes buf^1 (tile j+1), retires all reads of buf (tile j)
    __syncthreads();
  }
  // epilogue: normalize rows (ls lives at lane l31==row) and store ctx
  float inv = 1.0f / ls;
#pragma unroll
  for (int r = 0; r < 16; ++r) {
    int ql = (r & 3) + 8 * (r >> 2) + 4 * hh;
    float ivr = __shfl(inv, ql, 64);
    u16* cb = ctx + ((size_t)(b * T_ + qbase + w * 32 + ql)) * 4096 + h * HD_ + l31;
    cb[0]  = f2bf(acc[0][r] * ivr);
    cb[32] = f2bf(acc[1][r] * ivr);
    cb[64] = f2bf(acc[2][r] * ivr);
    cb[96] = f2bf(acc[3][r] * ivr);
  }
}

// ---------------- launch ----------------
extern "C" void kernel_launch(void* const* d_in, const int* in_sizes, int n_in,
                              void* d_out, int out_size, void* d_ws, size_t ws_size,
                              hipStream_t stream) {
  const float* x      = (const float*)d_in[0];
  // d_in[1] = mask (derived analytically; unused)
  const float* cosT   = (const float*)d_in[2];
  const float* sinT   = (const float*)d_in[3];
  const int*   sp     = (const int*)d_in[4];
  const float* prev_k = (const float*)d_in[5];
  const float* prev_v = (const float*)d_in[6];
  const float* q_w    = (const float*)d_in[7];
  const float* k_w    = (const float*)d_in[8];
  const float* v_w    = (const float*)d_in[9];
  const float* o_w    = (const float*)d_in[10];

  float* out   = (float*)d_out;
  float* k_all = out + (size_t)B_ * T_ * H_ * HD_;      // +8388608
  float* v_all = k_all + (size_t)B_ * G_ * S_ * HD_;    // +16777216

  char* w = (char*)d_ws;
  u16* wt_qkv = (u16*)(w);                 // [6144][4096] bf16   50331648 B
  u16* wt_o   = (u16*)(w + 50331648);      // [4096][4096] bf16   33554432 B
  u16* x_bf   = (u16*)(w + 83886080);      // [2048][4096] bf16   16777216 B
  u16* qkv_bf = (u16*)(w + 100663296);     // [2048][6144] bf16   25165824 B
  u16* q_rope = (u16*)(w + 125829120);     // [4][32][512][128]   16777216 B
  u16* k_bf   = (u16*)(w + 142606336);     // [4][8][4096][128]   33554432 B
  u16* v_t    = (u16*)(w + 176160768);     // [4][8][128][4096]   33554432 B
  u16* ctx    = (u16*)(w + 209715200);     // [2048][4096]        16777216 B
  if (ws_size < 226492416ull) return;      // workspace too small -> bench will flag it

  k_prep_w<<<dim3(64, 288), 256, 0, stream>>>(q_w, k_w, v_w, o_w, x, wt_qkv, wt_o, x_bf);
  k_prep_kv<<<dim3(504, 32), 256, 0, stream>>>(prev_k, prev_v, k_all, v_all, k_bf, v_t);
  k_gemm2<256, 192, false><<<256, 512, 0, stream>>>(x_bf, wt_qkv, qkv_bf, M_, NQKV, 4096);
  k_rope<<<2048, 256, 0, stream>>>(qkv_bf, cosT, sinT, sp, q_rope, k_bf, k_all, v_all);
  k_tv_new<<<dim3(16, 32), 256, 0, stream>>>(qkv_bf, v_t);
  k_attn<<<256, 512, 0, stream>>>(q_rope, k_bf, v_t, sp, ctx);
  k_gemm2<128, 256, true><<<256, 512, 0, stream>>>(ctx, wt_o, out, M_, 4096, 4096);
}